// Round 11
// baseline (187.324 us; speedup 1.0000x reference)
//
#include <hip/hip_runtime.h>

typedef __bf16 bf16;
typedef __bf16 bf16x4 __attribute__((ext_vector_type(4)));
typedef __bf16 bf16x8 __attribute__((ext_vector_type(8)));
typedef float f32x4 __attribute__((ext_vector_type(4)));
typedef float f32x16 __attribute__((ext_vector_type(16)));

#define MFMA16(a, b, c) __builtin_amdgcn_mfma_f32_16x16x32_bf16((a), (b), (c), 0, 0, 0)
#define MFMA32(a, b, c) __builtin_amdgcn_mfma_f32_32x32x16_bf16((a), (b), (c), 0, 0, 0)
// swap vdst's high 32 lanes with vsrc's low 32 lanes (both regs updated).
// ONLY safe when a and b hold distinct values (else regalloc may coalesce
// them into one VGPR and the swap degenerates) -- R6 post-mortem.
#define PLSWAP(a, b) asm("v_permlane32_swap_b32 %0, %1" : "+v"(a), "+v"(b))

// async global->LDS, 16B per lane. Dest must be linear in lane order (HW uses
// wave-uniform base + lane*16); swizzle is applied to the SOURCE address.
typedef const void __attribute__((address_space(1)))* gas1;
typedef void __attribute__((address_space(3)))* las3;
#define ASYNC16(g, l) __builtin_amdgcn_global_load_lds((gas1)(g), (las3)(l), 16, 0, 0)

__device__ __forceinline__ unsigned pk2(float lo, float hi) {
  unsigned short a = __builtin_bit_cast(unsigned short, (bf16)lo);
  unsigned short b = __builtin_bit_cast(unsigned short, (bf16)hi);
  return (unsigned)a | ((unsigned)b << 16);
}

// ---------------------------------------------------------------------------
// fp32 -> bf16 elementwise convert (vectorized: 8 elems/thread)
__global__ __launch_bounds__(256) void cvt_f32_bf16(const float* __restrict__ in,
                                                    bf16* __restrict__ out, int n8) {
  int i = blockIdx.x * 256 + threadIdx.x;
  if (i < n8) {
    float4 a = ((const float4*)in)[2 * i];
    float4 b = ((const float4*)in)[2 * i + 1];
    bf16x8 v;
    v[0] = (bf16)a.x; v[1] = (bf16)a.y; v[2] = (bf16)a.z; v[3] = (bf16)a.w;
    v[4] = (bf16)b.x; v[5] = (bf16)b.y; v[6] = (bf16)b.z; v[7] = (bf16)b.w;
    ((bf16x8*)out)[i] = v;
  }
}

// ---------------------------------------------------------------------------
// W[K][N] fp32 -> WT[N][K] bf16   (K,N multiples of 32)
__global__ __launch_bounds__(256) void transpose_cvt(const float* __restrict__ in,
                                                     bf16* __restrict__ out, int K, int N) {
  __shared__ float tile[32][33];
  int tx = threadIdx.x, ty = threadIdx.y;  // block (32,8)
  int n0 = blockIdx.x * 32, k0 = blockIdx.y * 32;
#pragma unroll
  for (int i = 0; i < 4; i++) tile[ty + i * 8][tx] = in[(long)(k0 + ty + i * 8) * N + n0 + tx];
  __syncthreads();
#pragma unroll
  for (int i = 0; i < 4; i++)
    out[(long)(n0 + ty + i * 8) * K + k0 + tx] = (bf16)tile[tx][ty + i * 8];
}

// Fused Wq/Wk/Wv transpose (512x512 each), z selects the matrix.
__global__ __launch_bounds__(256) void transpose_cvt_qkv(const float* __restrict__ Wq,
                                                         const float* __restrict__ Wk,
                                                         const float* __restrict__ Wv,
                                                         bf16* __restrict__ out) {
  __shared__ float tile[32][33];
  int tx = threadIdx.x, ty = threadIdx.y;  // block (32,8)
  int which = blockIdx.z;
  const float* in = which == 0 ? Wq : (which == 1 ? Wk : Wv);
  bf16* o = out + (long)which * 512 * 512;
  int n0 = blockIdx.x * 32, k0 = blockIdx.y * 32;
#pragma unroll
  for (int i = 0; i < 4; i++) tile[ty + i * 8][tx] = in[(long)(k0 + ty + i * 8) * 512 + n0 + tx];
  __syncthreads();
#pragma unroll
  for (int i = 0; i < 4; i++)
    o[(long)(n0 + ty + i * 8) * 512 + k0 + tx] = (bf16)tile[tx][ty + i * 8];
}

// ---------------------------------------------------------------------------
__global__ __launch_bounds__(256) void concat_bias(const float* __restrict__ bq,
                                                   const float* __restrict__ bk,
                                                   const float* __restrict__ bv,
                                                   float* __restrict__ outb) {
  int i = blockIdx.x * 256 + threadIdx.x;
  if (i < 512) outb[i] = bq[i];
  else if (i < 1024) outb[i] = bk[i - 512];
  else if (i < 1536) outb[i] = bv[i - 1024];
}

// ---------------------------------------------------------------------------
// C[M,N](OutT) = act(A[M,K](bf16) @ BT[N,K](bf16)^T + bias) [+ resid]
// 128x128 tile, BK=64, 4 waves (2x2, 64x64/wave = m97 FLOP/LDS-byte ratio),
// 16x16x32 MFMA. global_load_lds staging: linear LDS dest, XOR-swizzled
// (involution) source, swizzled reads (rule #21). R5-proven structure.
// VSPLIT: blocks with bcol>=1024 write the V third transposed into
// vt[b*8+h][d][s] instead of C (feeds attention without a transpose pass).
template <int ACT, int RESID, int VSPLIT, typename OutT>
__global__ __launch_bounds__(256, 2)
void gemm_bt(const bf16* __restrict__ A, const bf16* __restrict__ BT,
             const float* __restrict__ bias, const bf16* __restrict__ resid,
             OutT* __restrict__ C, bf16* __restrict__ vt,
             int K, int lda, int ldb, int ldc) {
  __shared__ __align__(16) char As[128 * 128];  // 128 rows x 64 bf16 (128B/row)
  __shared__ __align__(16) char Bs[128 * 128];
  const int tid = threadIdx.x;
  const int l = tid & 63, w = tid >> 6;
  const int lrow = l & 15, lhi = l >> 4;
  const int wr = w >> 1, wc = w & 1;
  const long brow = (long)blockIdx.y * 128;
  const long bcol = (long)blockIdx.x * 128;

  f32x4 zero = {0.f, 0.f, 0.f, 0.f};
  f32x4 acc[4][4];
#pragma unroll
  for (int m = 0; m < 4; m++)
#pragma unroll
    for (int n = 0; n < 4; n++) acc[m][n] = zero;

  for (int kt = 0; kt < K; kt += 64) {
    __syncthreads();
#pragma unroll
    for (int c = 0; c < 4; c++) {
      int idx = c * 256 + tid;                    // 16B chunk id (lane-consecutive)
      int row = idx >> 3;                          // 8 chunks per 128B row
      int cole = ((idx & 7) ^ (row & 7)) * 8;      // swizzled source column
      ASYNC16(A + (brow + row) * lda + kt + cole, As + idx * 16);
      ASYNC16(BT + (bcol + row) * ldb + kt + cole, Bs + idx * 16);
    }
    __syncthreads();  // compiler drains vmcnt before s_barrier
    bf16x8 af[4][2], bfr[4][2];
#pragma unroll
    for (int m = 0; m < 4; m++) {
      int row = wr * 64 + m * 16 + lrow;
      int base = row * 128 + lhi * 16;
      int sw = (row & 7) << 4;
      af[m][0] = *(const bf16x8*)(As + (base ^ sw));
      af[m][1] = *(const bf16x8*)(As + ((base + 64) ^ sw));
    }
#pragma unroll
    for (int n = 0; n < 4; n++) {
      int row = wc * 64 + n * 16 + lrow;
      int base = row * 128 + lhi * 16;
      int sw = (row & 7) << 4;
      bfr[n][0] = *(const bf16x8*)(Bs + (base ^ sw));
      bfr[n][1] = *(const bf16x8*)(Bs + ((base + 64) ^ sw));
    }
#pragma unroll
    for (int m = 0; m < 4; m++)
#pragma unroll
      for (int n = 0; n < 4; n++) {
        acc[m][n] = MFMA16(af[m][0], bfr[n][0], acc[m][n]);
        acc[m][n] = MFMA16(af[m][1], bfr[n][1], acc[m][n]);
      }
  }

  if (VSPLIT && bcol >= 1024) {
    // V third -> vt[b*8+h][d][s]; rows brow.. are b*1024+s, cols are 1024+h*64+d
#pragma unroll
    for (int m = 0; m < 4; m++) {
#pragma unroll
      for (int n = 0; n < 4; n++) {
        long col = bcol + wc * 64 + n * 16 + lrow;
        float bv = bias[col];
        int cc = (int)col - 1024;
        int hh = cc >> 6, dd = cc & 63;
        long row0 = brow + wr * 64 + m * 16 + lhi * 4;
        int b = (int)(row0 >> 10), s0 = (int)(row0 & 1023);
        bf16x4 v4;
#pragma unroll
        for (int r = 0; r < 4; r++) v4[r] = (bf16)(acc[m][n][r] + bv);
        *(bf16x4*)(vt + ((long)(b * 8 + hh) * 64 + dd) * 1024 + s0) = v4;
      }
    }
    return;
  }

#pragma unroll
  for (int m = 0; m < 4; m++) {
#pragma unroll
    for (int n = 0; n < 4; n++) {
      long col = bcol + wc * 64 + n * 16 + lrow;
      float bv = bias[col];
#pragma unroll
      for (int r = 0; r < 4; r++) {
        long row = brow + wr * 64 + m * 16 + lhi * 4 + r;
        float v = acc[m][n][r] + bv;
        if (ACT) v = v > 0.f ? v : 0.01f * v;
        if (RESID) v += (float)resid[row * ldc + col];
        C[row * ldc + col] = (OutT)v;
      }
    }
  }
}

// ---------------------------------------------------------------------------
// Flash attention, swapped-operand 32x32x16 (T12), NO-LDS variant (m169
// lesson: K/V per (b,h) = 256KB, L2-resident -- staging was pure overhead).
// Each wave reads K/V MFMA fragments directly from global; waves independent,
// zero barriers. Block = 2 waves x 32 q-rows = 64 q; grid 1024 (1-D):
// id = qt*64 + (b*8+h) so id%8 = h -> all blocks of head h land on XCD h;
// per-XCD K/V working set = 8 batches x 256KB = 2MB <= 4MB L2.
// Softmax/repack/PV math = R5/R8-proven form verbatim.
// Reference quirk: softmax FIRST, then /sqrt(512).
__global__ __launch_bounds__(128, 4)
void attn_fwd(const bf16* __restrict__ QKV, const bf16* __restrict__ Vtg,
              bf16* __restrict__ attn_out) {
  const int bid = blockIdx.x;
  const int bh = bid & 63;   // b*8 + h
  const int qt = bid >> 6;   // q-tile 0..15
  const int b = bh >> 3, h = bh & 7;
  const int tid = threadIdx.x;
  const int l = tid & 63, w = tid >> 6;  // w in 0..1
  const int q = l & 31, hi = l >> 5;
  const long rowbase = (long)b * 1024;
  const int q0 = qt * 64;
  const float LOG2E = 1.4426950408889634f;

  // lane-invariant fragment base pointers
  const bf16* kb = QKV + 512 + rowbase * 1536 + h * 64 + hi * 8;   // + krow*1536 + sd*16
  const bf16* vb = Vtg + (long)bh * 64 * 1024 + hi * 8;            // + d*1024 + s-offset

  // Q fragments (B-operand): aq[sd][j] = Q[qrow][sd*16 + hi*8 + j]
  bf16x8 aq[4];
  {
    long qrow = rowbase + q0 + w * 32 + q;
    const bf16* p = QKV + qrow * 1536 + h * 64 + hi * 8;
    aq[0] = *(const bf16x8*)(p);
    aq[1] = *(const bf16x8*)(p + 16);
    aq[2] = *(const bf16x8*)(p + 32);
    aq[3] = *(const bf16x8*)(p + 48);
  }
  asm volatile("" ::"v"(aq[0]), "v"(aq[1]), "v"(aq[2]), "v"(aq[3]));

  f32x16 o0, o1;
#pragma unroll
  for (int i = 0; i < 16; i++) { o0[i] = 0.f; o1[i] = 0.f; }
  float m_run = -1e30f, l_run = 0.f;

  for (int kt = 0; kt < 16; ++kt) {
    // K fragments direct from global: kf[g][sd] = K[kt*64+g*32+q][sd*16+hi*8..+8]
    bf16x8 kf0[4], kf1[4];
    {
      const bf16* k0p = kb + (long)(kt * 64 + q) * 1536;
      const bf16* k1p = kb + (long)(kt * 64 + 32 + q) * 1536;
#pragma unroll
      for (int sd = 0; sd < 4; sd++) {
        kf0[sd] = *(const bf16x8*)(k0p + sd * 16);
        kf1[sd] = *(const bf16x8*)(k1p + sd * 16);
      }
    }

    // S^T = K Q^T : lane holds col q=l&31, 32 keys across regs/halves
    f32x16 s0, s1;
#pragma unroll
    for (int i = 0; i < 16; i++) { s0[i] = 0.f; s1[i] = 0.f; }
    __builtin_amdgcn_s_setprio(1);
#pragma unroll
    for (int sd = 0; sd < 4; sd++) s0 = MFMA32(kf0[sd], aq[sd], s0);
#pragma unroll
    for (int sd = 0; sd < 4; sd++) s1 = MFMA32(kf1[sd], aq[sd], s1);
    __builtin_amdgcn_s_setprio(0);

    // V fragments direct from global: vf[sub][ks] = Vt[sub*32+q][kt*64+ks*16+hi*8..+8]
    // issued here so their L2 latency hides under the softmax VALU work
    bf16x8 vf0[4], vf1[4];
    {
      const bf16* v0p = vb + (long)q * 1024 + kt * 64;
      const bf16* v1p = vb + (long)(32 + q) * 1024 + kt * 64;
#pragma unroll
      for (int ks = 0; ks < 4; ks++) {
        vf0[ks] = *(const bf16x8*)(v0p + ks * 16);
        vf1[ks] = *(const bf16x8*)(v1p + ks * 16);
      }
    }

    // in-register online softmax (R5/R8-proven serial form)
    float tmax = s0[0];
#pragma unroll
    for (int i = 1; i < 16; i++) tmax = fmaxf(tmax, s0[i]);
#pragma unroll
    for (int i = 0; i < 16; i++) tmax = fmaxf(tmax, s1[i]);
    tmax = fmaxf(tmax, __shfl_xor(tmax, 32));
    float mn = fmaxf(m_run, tmax);
    float al = __builtin_exp2f((m_run - mn) * LOG2E);
    float mh = mn * LOG2E;
    m_run = mn;
    float p0[16], p1[16];
    float ps = 0.f;
#pragma unroll
    for (int i = 0; i < 16; i++) {
      p0[i] = __builtin_exp2f(__builtin_fmaf(s0[i], LOG2E, -mh));
      ps += p0[i];
    }
#pragma unroll
    for (int i = 0; i < 16; i++) {
      p1[i] = __builtin_exp2f(__builtin_fmaf(s1[i], LOG2E, -mh));
      ps += p1[i];
    }
    ps += __shfl_xor(ps, 32);
    l_run = l_run * al + ps;
#pragma unroll
    for (int i = 0; i < 16; i++) { o0[i] *= al; o1[i] *= al; }

    // repack P (C-layout) -> 4 B-fragments pa[ks] (k = ks*16 + hi*8 + j)
    bf16x8 pa[4];
    {
      unsigned a0 = pk2(p0[0], p0[1]), b0 = pk2(p0[4], p0[5]);
      unsigned a1 = pk2(p0[2], p0[3]), b1 = pk2(p0[6], p0[7]);
      unsigned a2 = pk2(p0[8], p0[9]), b2 = pk2(p0[12], p0[13]);
      unsigned a3 = pk2(p0[10], p0[11]), b3 = pk2(p0[14], p0[15]);
      PLSWAP(a0, b0); PLSWAP(a1, b1); PLSWAP(a2, b2); PLSWAP(a3, b3);
      uint4 w0 = {a0, a1, b0, b1};
      uint4 w1 = {a2, a3, b2, b3};
      pa[0] = __builtin_bit_cast(bf16x8, w0);
      pa[1] = __builtin_bit_cast(bf16x8, w1);
      unsigned c0 = pk2(p1[0], p1[1]), d0 = pk2(p1[4], p1[5]);
      unsigned c1 = pk2(p1[2], p1[3]), d1 = pk2(p1[6], p1[7]);
      unsigned c2 = pk2(p1[8], p1[9]), d2 = pk2(p1[12], p1[13]);
      unsigned c3 = pk2(p1[10], p1[11]), d3 = pk2(p1[14], p1[15]);
      PLSWAP(c0, d0); PLSWAP(c1, d1); PLSWAP(c2, d2); PLSWAP(c3, d3);
      uint4 w2 = {c0, c1, d0, d1};
      uint4 w3 = {c2, c3, d2, d3};
      pa[2] = __builtin_bit_cast(bf16x8, w2);
      pa[3] = __builtin_bit_cast(bf16x8, w3);
    }

    // O^T += V^T P^T : lane holds col q, d-rows in regs
    __builtin_amdgcn_s_setprio(1);
#pragma unroll
    for (int ks = 0; ks < 4; ks++) o0 = MFMA32(vf0[ks], pa[ks], o0);
#pragma unroll
    for (int ks = 0; ks < 4; ks++) o1 = MFMA32(vf1[ks], pa[ks], o1);
    __builtin_amdgcn_s_setprio(0);
  }

  // epilogue: quirk scale 1/sqrt(512) AFTER softmax; O^T -> row-major out
  float fac = 0.044194173824159216f / l_run;
  long qrow = rowbase + q0 + w * 32 + q;
  bf16* op = attn_out + qrow * 512 + h * 64;
#pragma unroll
  for (int t = 0; t < 4; t++) {
    bf16x4 v0, v1;
#pragma unroll
    for (int u = 0; u < 4; u++) {
      v0[u] = (bf16)(o0[4 * t + u] * fac);
      v1[u] = (bf16)(o1[4 * t + u] * fac);
    }
    *(bf16x4*)(op + 8 * t + 4 * hi) = v0;
    *(bf16x4*)(op + 32 + 8 * t + 4 * hi) = v1;
  }
}

// ---------------------------------------------------------------------------
// ln = LayerNorm(seq_f32 + attn_bf16) * gamma + beta   (one block per row)
__global__ __launch_bounds__(256) void ln_kernel(const float* __restrict__ seq,
                                                 const bf16* __restrict__ attn,
                                                 const float* __restrict__ gamma,
                                                 const float* __restrict__ beta,
                                                 bf16* __restrict__ out) {
  int row = blockIdx.x;
  int tid = threadIdx.x;
  long base = (long)row * 512;
  float x0 = seq[base + tid] + (float)attn[base + tid];
  float x1 = seq[base + 256 + tid] + (float)attn[base + 256 + tid];
  float s = x0 + x1, ss = x0 * x0 + x1 * x1;
#pragma unroll
  for (int mm = 1; mm < 64; mm <<= 1) {
    s += __shfl_xor(s, mm);
    ss += __shfl_xor(ss, mm);
  }
  __shared__ float red[8];
  int w = tid >> 6, l = tid & 63;
  if (l == 0) { red[w] = s; red[4 + w] = ss; }
  __syncthreads();
  s = red[0] + red[1] + red[2] + red[3];
  ss = red[4] + red[5] + red[6] + red[7];
  float mu = s * (1.f / 512.f);
  float var = ss * (1.f / 512.f) - mu * mu;
  float rs = rsqrtf(var + 1e-5f);
  out[base + tid] = (bf16)((x0 - mu) * rs * gamma[tid] + beta[tid]);
  out[base + 256 + tid] = (bf16)((x1 - mu) * rs * gamma[tid + 256] + beta[tid + 256]);
}

// ---------------------------------------------------------------------------
extern "C" void kernel_launch(void* const* d_in, const int* in_sizes, int n_in,
                              void* d_out, int out_size, void* d_ws, size_t ws_size,
                              hipStream_t stream) {
  const float* seq = (const float*)d_in[0];
  const float* Wq = (const float*)d_in[1];
  const float* bq = (const float*)d_in[2];
  const float* Wk = (const float*)d_in[3];
  const float* bk = (const float*)d_in[4];
  const float* Wv = (const float*)d_in[5];
  const float* bv = (const float*)d_in[6];
  const float* W1 = (const float*)d_in[7];
  const float* b1 = (const float*)d_in[8];
  const float* W2 = (const float*)d_in[9];
  const float* b2 = (const float*)d_in[10];
  const float* gamma = (const float*)d_in[11];
  const float* beta = (const float*)d_in[12];
  float* out = (float*)d_out;  // reference output dtype is float32

  // workspace layout (bytes)
  char* ws = (char*)d_ws;
  if (ws_size < 89659392u) return;  // loud failure signature if ws too small
  bf16* seq_bf = (bf16*)(ws + 0);          //  8192x512   bf16  (8,388,608)
  bf16* qkvT = (bf16*)(ws + 8388608);      //  1536x512   bf16  (1,572,864)
  bf16* W1T = (bf16*)(ws + 9961472);       //  2048x512   bf16  (2,097,152)
  bf16* W2T = (bf16*)(ws + 12058624);      //  512x2048   bf16  (2,097,152)
  float* bqkv = (float*)(ws + 14155776);   //  1536       f32   (6,144)
  bf16* QKV = (bf16*)(ws + 14161920);      //  8192x1536  bf16  (25,165,824; V third unused)
  bf16* attn = (bf16*)(ws + 39327744);     //  8192x512   bf16  (8,388,608)
  bf16* ln = (bf16*)(ws + 47716352);       //  8192x512   bf16  (8,388,608)
  bf16* hidden = (bf16*)(ws + 56104960);   //  8192x2048  bf16  (33,554,432)
  bf16* vt = (bf16*)(ws + 56104960);       //  64x64x1024 bf16  (8.4MB, aliases hidden:
                                           //  written by QKV gemm, read by attn,
                                           //  dead before FFN1 overwrites hidden)

  cvt_f32_bf16<<<2048, 256, 0, stream>>>(seq, seq_bf, 524288);
  transpose_cvt_qkv<<<dim3(16, 16, 3), dim3(32, 8), 0, stream>>>(Wq, Wk, Wv, qkvT);
  transpose_cvt<<<dim3(64, 16), dim3(32, 8), 0, stream>>>(W1, W1T, 512, 2048);
  transpose_cvt<<<dim3(16, 64), dim3(32, 8), 0, stream>>>(W2, W2T, 2048, 512);
  concat_bias<<<6, 256, 0, stream>>>(bq, bk, bv, bqkv);

  // QKV = seq_bf @ [Wq|Wk|Wv] + bias : M=8192 N=1536 K=512
  // Q,K cols -> QKV row-major; V cols -> vt[b*8+h][d][s] (transposed, fused)
  gemm_bt<0, 0, 1, bf16><<<dim3(12, 64), 256, 0, stream>>>(
      seq_bf, qkvT, bqkv, (const bf16*)nullptr, QKV, vt, 512, 512, 512, 1536);
  attn_fwd<<<1024, 128, 0, stream>>>(QKV, vt, attn);
  ln_kernel<<<8192, 256, 0, stream>>>(seq, attn, gamma, beta, ln);
  // hidden = leaky_relu(ln @ W1 + b1) : M=8192 N=2048 K=512  (overwrites vt, OK)
  gemm_bt<1, 0, 0, bf16><<<dim3(16, 64), 256, 0, stream>>>(
      ln, W1T, b1, (const bf16*)nullptr, hidden, (bf16*)nullptr, 512, 512, 512, 2048);
  // out = ln + hidden @ W2 + b2 : M=8192 N=512 K=2048
  gemm_bt<0, 1, 0, float><<<dim3(4, 64), 256, 0, stream>>>(
      hidden, W2T, b2, ln, out, (bf16*)nullptr, 2048, 2048, 2048, 512);
}

// Round 12
// 143.899 us; speedup vs baseline: 1.3018x; 1.3018x over previous
//
#include <hip/hip_runtime.h>

typedef __bf16 bf16;
typedef __bf16 bf16x4 __attribute__((ext_vector_type(4)));
typedef __bf16 bf16x8 __attribute__((ext_vector_type(8)));
typedef float f32x4 __attribute__((ext_vector_type(4)));
typedef float f32x16 __attribute__((ext_vector_type(16)));

#define MFMA16(a, b, c) __builtin_amdgcn_mfma_f32_16x16x32_bf16((a), (b), (c), 0, 0, 0)
#define MFMA32(a, b, c) __builtin_amdgcn_mfma_f32_32x32x16_bf16((a), (b), (c), 0, 0, 0)
// swap vdst's high 32 lanes with vsrc's low 32 lanes (both regs updated).
// ONLY safe when a and b hold distinct values (else regalloc may coalesce
// them into one VGPR and the swap degenerates) -- R6 post-mortem.
#define PLSWAP(a, b) asm("v_permlane32_swap_b32 %0, %1" : "+v"(a), "+v"(b))

// async global->LDS, 16B per lane. Dest must be linear in lane order (HW uses
// wave-uniform base + lane*16); swizzle is applied to the SOURCE address.
typedef const void __attribute__((address_space(1)))* gas1;
typedef void __attribute__((address_space(3)))* las3;
#define ASYNC16(g, l) __builtin_amdgcn_global_load_lds((gas1)(g), (las3)(l), 16, 0, 0)

__device__ __forceinline__ unsigned pk2(float lo, float hi) {
  unsigned short a = __builtin_bit_cast(unsigned short, (bf16)lo);
  unsigned short b = __builtin_bit_cast(unsigned short, (bf16)hi);
  return (unsigned)a | ((unsigned)b << 16);
}

// ---------------------------------------------------------------------------
// Fused pre-pass: one launch replaces {cvt, Wq/Wk/Wv transpose, W1T, W2T,
// concat_bias}. Block-id ranges select the sub-task; branches are
// block-uniform; barriers only inside transpose ranges (per-block, legal).
//   [0,2048)       : seq f32 -> bf16 (8 elems/thread)
//   [2048,2816)    : Wq/Wk/Wv 512x512 transpose+cvt (256 blocks each)
//   [2816,3840)    : W1 [512][2048] -> W1T [2048][512]
//   [3840,4864)    : W2 [2048][512] -> W2T [512][2048]
//   [4864,4870)    : bias concat (1536 floats)
__global__ __launch_bounds__(256) void prep_kernel(
    const float* __restrict__ seq, const float* __restrict__ Wq,
    const float* __restrict__ Wk, const float* __restrict__ Wv,
    const float* __restrict__ W1, const float* __restrict__ W2,
    const float* __restrict__ bq, const float* __restrict__ bk,
    const float* __restrict__ bv, bf16* __restrict__ seq_bf,
    bf16* __restrict__ qkvT, bf16* __restrict__ W1T, bf16* __restrict__ W2T,
    float* __restrict__ bqkv) {
  __shared__ float tile[32][33];
  const int blk = blockIdx.x;
  const int tid = threadIdx.x;

  if (blk < 2048) {  // cvt f32->bf16
    int i = blk * 256 + tid;
    float4 a = ((const float4*)seq)[2 * i];
    float4 b = ((const float4*)seq)[2 * i + 1];
    bf16x8 v;
    v[0] = (bf16)a.x; v[1] = (bf16)a.y; v[2] = (bf16)a.z; v[3] = (bf16)a.w;
    v[4] = (bf16)b.x; v[5] = (bf16)b.y; v[6] = (bf16)b.z; v[7] = (bf16)b.w;
    ((bf16x8*)seq_bf)[i] = v;
    return;
  }

  const int tx = tid & 31, ty = tid >> 5;  // (32,8) remap for transposes
  const float* in;
  bf16* out;
  int N, K, bx, by;
  if (blk < 3840) {
    if (blk < 2816) {  // Wq/Wk/Wv: 256 blocks each, N=K=512
      int t = blk - 2048;
      int which = t >> 8;
      int r = t & 255;
      in = which == 0 ? Wq : (which == 1 ? Wk : Wv);
      out = qkvT + (long)which * 512 * 512;
      N = 512; K = 512;
      bx = r & 15; by = r >> 4;
    } else {  // W1: N=2048, K=512, grid (64,16)
      int t = blk - 2816;
      in = W1; out = W1T; N = 2048; K = 512;
      bx = t & 63; by = t >> 6;
    }
  } else if (blk < 4864) {  // W2: N=512, K=2048, grid (16,64)
    int t = blk - 3840;
    in = W2; out = W2T; N = 512; K = 2048;
    bx = t & 15; by = t >> 4;
  } else {  // concat bias
    int i = (blk - 4864) * 256 + tid;
    if (i < 512) bqkv[i] = bq[i];
    else if (i < 1024) bqkv[i] = bk[i - 512];
    else if (i < 1536) bqkv[i] = bv[i - 1024];
    return;
  }

  int n0 = bx * 32, k0 = by * 32;
#pragma unroll
  for (int i = 0; i < 4; i++) tile[ty + i * 8][tx] = in[(long)(k0 + ty + i * 8) * N + n0 + tx];
  __syncthreads();
#pragma unroll
  for (int i = 0; i < 4; i++)
    out[(long)(n0 + ty + i * 8) * K + k0 + tx] = (bf16)tile[tx][ty + i * 8];
}

// ---------------------------------------------------------------------------
// C[M,N](OutT) = act(A[M,K](bf16) @ BT[N,K](bf16)^T + bias) [+ resid]
// 128x128 tile, BK=64, 4 waves (2x2, 64x64/wave = m97 FLOP/LDS-byte ratio),
// 16x16x32 MFMA. global_load_lds staging: linear LDS dest, XOR-swizzled
// (involution) source, swizzled reads (rule #21). R5-proven structure.
// VSPLIT: blocks with bcol>=1024 write the V third transposed into
// vt[b*8+h][d][s] instead of C (feeds attention without a transpose pass).
template <int ACT, int RESID, int VSPLIT, typename OutT>
__global__ __launch_bounds__(256, 2)
void gemm_bt(const bf16* __restrict__ A, const bf16* __restrict__ BT,
             const float* __restrict__ bias, const bf16* __restrict__ resid,
             OutT* __restrict__ C, bf16* __restrict__ vt,
             int K, int lda, int ldb, int ldc) {
  __shared__ __align__(16) char As[128 * 128];  // 128 rows x 64 bf16 (128B/row)
  __shared__ __align__(16) char Bs[128 * 128];
  const int tid = threadIdx.x;
  const int l = tid & 63, w = tid >> 6;
  const int lrow = l & 15, lhi = l >> 4;
  const int wr = w >> 1, wc = w & 1;
  const long brow = (long)blockIdx.y * 128;
  const long bcol = (long)blockIdx.x * 128;

  f32x4 zero = {0.f, 0.f, 0.f, 0.f};
  f32x4 acc[4][4];
#pragma unroll
  for (int m = 0; m < 4; m++)
#pragma unroll
    for (int n = 0; n < 4; n++) acc[m][n] = zero;

  for (int kt = 0; kt < K; kt += 64) {
    __syncthreads();
#pragma unroll
    for (int c = 0; c < 4; c++) {
      int idx = c * 256 + tid;                    // 16B chunk id (lane-consecutive)
      int row = idx >> 3;                          // 8 chunks per 128B row
      int cole = ((idx & 7) ^ (row & 7)) * 8;      // swizzled source column
      ASYNC16(A + (brow + row) * lda + kt + cole, As + idx * 16);
      ASYNC16(BT + (bcol + row) * ldb + kt + cole, Bs + idx * 16);
    }
    __syncthreads();  // compiler drains vmcnt before s_barrier
    bf16x8 af[4][2], bfr[4][2];
#pragma unroll
    for (int m = 0; m < 4; m++) {
      int row = wr * 64 + m * 16 + lrow;
      int base = row * 128 + lhi * 16;
      int sw = (row & 7) << 4;
      af[m][0] = *(const bf16x8*)(As + (base ^ sw));
      af[m][1] = *(const bf16x8*)(As + ((base + 64) ^ sw));
    }
#pragma unroll
    for (int n = 0; n < 4; n++) {
      int row = wc * 64 + n * 16 + lrow;
      int base = row * 128 + lhi * 16;
      int sw = (row & 7) << 4;
      bfr[n][0] = *(const bf16x8*)(Bs + (base ^ sw));
      bfr[n][1] = *(const bf16x8*)(Bs + ((base + 64) ^ sw));
    }
#pragma unroll
    for (int m = 0; m < 4; m++)
#pragma unroll
      for (int n = 0; n < 4; n++) {
        acc[m][n] = MFMA16(af[m][0], bfr[n][0], acc[m][n]);
        acc[m][n] = MFMA16(af[m][1], bfr[n][1], acc[m][n]);
      }
  }

  if (VSPLIT && bcol >= 1024) {
    // V third -> vt[b*8+h][d][s]; rows brow.. are b*1024+s, cols are 1024+h*64+d
#pragma unroll
    for (int m = 0; m < 4; m++) {
#pragma unroll
      for (int n = 0; n < 4; n++) {
        long col = bcol + wc * 64 + n * 16 + lrow;
        float bv = bias[col];
        int cc = (int)col - 1024;
        int hh = cc >> 6, dd = cc & 63;
        long row0 = brow + wr * 64 + m * 16 + lhi * 4;
        int b = (int)(row0 >> 10), s0 = (int)(row0 & 1023);
        bf16x4 v4;
#pragma unroll
        for (int r = 0; r < 4; r++) v4[r] = (bf16)(acc[m][n][r] + bv);
        *(bf16x4*)(vt + ((long)(b * 8 + hh) * 64 + dd) * 1024 + s0) = v4;
      }
    }
    return;
  }

#pragma unroll
  for (int m = 0; m < 4; m++) {
#pragma unroll
    for (int n = 0; n < 4; n++) {
      long col = bcol + wc * 64 + n * 16 + lrow;
      float bv = bias[col];
#pragma unroll
      for (int r = 0; r < 4; r++) {
        long row = brow + wr * 64 + m * 16 + lhi * 4 + r;
        float v = acc[m][n][r] + bv;
        if (ACT) v = v > 0.f ? v : 0.01f * v;
        if (RESID) v += (float)resid[row * ldc + col];
        C[row * ldc + col] = (OutT)v;
      }
    }
  }
}

// ---------------------------------------------------------------------------
// Flash attention, swapped-operand 32x32x16 structure (T12) -- R8-proven
// config (the robust local optimum: dbuf-only, micro-VALU, KVBLK=128 and
// no-LDS variants all measured neutral-or-worse). QK^T computed as mfma(K,Q)
// so C-layout col = lane&31 = q-row -> softmax fully in-register (one
// shfl_xor(32) per reduce). PV as mfma(V^T, P^T) -> O^T also has col = q.
// P repack via pk-casts + 8 v_permlane32_swap_b32 (distinct-value PLSWAPs).
// Counted-vmcnt K/V dbuf. Reference quirk: softmax FIRST, then /sqrt(512).
// Grid (S/128, H, B), 4 waves, wave owns 32 q-rows; KVBLK=64.
__global__ __launch_bounds__(256, 2)
void attn_fwd(const bf16* __restrict__ QKV, const bf16* __restrict__ Vtg,
              bf16* __restrict__ attn_out) {
  __shared__ __align__(16) char Ks[2][64 * 128];  // [key][d] swizzled, dbuf
  __shared__ __align__(16) char Vs[2][64 * 128];  // [d][s] swizzled, dbuf
  const int tid = threadIdx.x;
  const int l = tid & 63, w = tid >> 6;
  const int q = l & 31, hi = l >> 5;
  const int h = blockIdx.y;
  const long rowbase = (long)blockIdx.z * 1024;
  const int q0 = blockIdx.x * 128;
  const float LOG2E = 1.4426950408889634f;

  const bf16* Kb = QKV + 512;
  const bf16* Vb = Vtg + ((long)blockIdx.z * 8 + h) * 64 * 1024;  // [64][1024]

  auto stage = [&](int buf, int kt) {
#pragma unroll
    for (int c = 0; c < 2; c++) {
      int idx = c * 256 + tid;
      int row = idx >> 3;
      int cole = ((idx & 7) ^ (row & 7)) * 8;
      ASYNC16(Kb + (rowbase + kt * 64 + row) * 1536 + h * 64 + cole, Ks[buf] + idx * 16);
      ASYNC16(Vb + row * 1024 + kt * 64 + cole, Vs[buf] + idx * 16);
    }
  };

  // Q fragments (B-operand): aq[sd][j] = Q[qrow][sd*16 + hi*8 + j]
  bf16x8 aq[4];
  {
    long qrow = rowbase + q0 + w * 32 + q;
    const bf16* p = QKV + qrow * 1536 + h * 64 + hi * 8;
    aq[0] = *(const bf16x8*)(p);
    aq[1] = *(const bf16x8*)(p + 16);
    aq[2] = *(const bf16x8*)(p + 32);
    aq[3] = *(const bf16x8*)(p + 48);
  }
  // pin Q loads complete BEFORE the pipeline starts, so the compiler's
  // load-use waitcnt can't drain the prefetch queue inside the loop
  asm volatile("" ::"v"(aq[0]), "v"(aq[1]), "v"(aq[2]), "v"(aq[3]));

  f32x16 o0, o1;
#pragma unroll
  for (int i = 0; i < 16; i++) { o0[i] = 0.f; o1[i] = 0.f; }
  float m_run = -1e30f, l_run = 0.f;

  stage(0, 0);
  int cur = 0;

  for (int kt = 0; kt < 16; ++kt) {
    // barrier A: all waves done READING buf cur^1 -> safe to overwrite
    asm volatile("" ::: "memory");
    __builtin_amdgcn_s_barrier();
    asm volatile("" ::: "memory");
    stage(cur ^ 1, (kt + 1) & 15);
    asm volatile("s_waitcnt vmcnt(4)" ::: "memory");  // older 4 (tile kt) landed
    __builtin_amdgcn_sched_barrier(0);
    __builtin_amdgcn_s_barrier();  // barrier B
    asm volatile("" ::: "memory");

    const char* Kc = Ks[cur];
    const char* Vc = Vs[cur];

    // S^T = K Q^T : lane holds col q=l&31, 32 keys across regs/halves
    f32x16 s0, s1;
#pragma unroll
    for (int i = 0; i < 16; i++) { s0[i] = 0.f; s1[i] = 0.f; }
    __builtin_amdgcn_s_setprio(1);
#pragma unroll
    for (int t = 0; t < 2; t++) {
      f32x16 c;
#pragma unroll
      for (int i = 0; i < 16; i++) c[i] = 0.f;
      int row = t * 32 + q;
      int sw = (row & 7) << 4;
#pragma unroll
      for (int sd = 0; sd < 4; sd++) {
        bf16x8 kf = *(const bf16x8*)(Kc + ((row * 128 + sd * 32 + hi * 16) ^ sw));
        c = MFMA32(kf, aq[sd], c);
      }
      if (t) s1 = c; else s0 = c;
    }
    __builtin_amdgcn_s_setprio(0);

    // in-register online softmax (lane owns q-row; halves share via 1 shfl)
    float tmax = s0[0];
#pragma unroll
    for (int i = 1; i < 16; i++) tmax = fmaxf(tmax, s0[i]);
#pragma unroll
    for (int i = 0; i < 16; i++) tmax = fmaxf(tmax, s1[i]);
    tmax = fmaxf(tmax, __shfl_xor(tmax, 32));
    float mn = fmaxf(m_run, tmax);
    float al = __builtin_exp2f((m_run - mn) * LOG2E);
    float mh = mn * LOG2E;
    m_run = mn;
    float p0[16], p1[16];
    float ps = 0.f;
#pragma unroll
    for (int i = 0; i < 16; i++) {
      p0[i] = __builtin_exp2f(__builtin_fmaf(s0[i], LOG2E, -mh));
      ps += p0[i];
    }
#pragma unroll
    for (int i = 0; i < 16; i++) {
      p1[i] = __builtin_exp2f(__builtin_fmaf(s1[i], LOG2E, -mh));
      ps += p1[i];
    }
    ps += __shfl_xor(ps, 32);
    l_run = l_run * al + ps;
#pragma unroll
    for (int i = 0; i < 16; i++) { o0[i] *= al; o1[i] *= al; }

    // repack P (C-layout) -> 4 B-fragments pa[ks] (k = ks*16 + hi*8 + j)
    bf16x8 pa[4];
    {
      unsigned a0 = pk2(p0[0], p0[1]), b0 = pk2(p0[4], p0[5]);
      unsigned a1 = pk2(p0[2], p0[3]), b1 = pk2(p0[6], p0[7]);
      unsigned a2 = pk2(p0[8], p0[9]), b2 = pk2(p0[12], p0[13]);
      unsigned a3 = pk2(p0[10], p0[11]), b3 = pk2(p0[14], p0[15]);
      PLSWAP(a0, b0); PLSWAP(a1, b1); PLSWAP(a2, b2); PLSWAP(a3, b3);
      uint4 w0 = {a0, a1, b0, b1};
      uint4 w1 = {a2, a3, b2, b3};
      pa[0] = __builtin_bit_cast(bf16x8, w0);
      pa[1] = __builtin_bit_cast(bf16x8, w1);
      unsigned c0 = pk2(p1[0], p1[1]), d0 = pk2(p1[4], p1[5]);
      unsigned c1 = pk2(p1[2], p1[3]), d1 = pk2(p1[6], p1[7]);
      unsigned c2 = pk2(p1[8], p1[9]), d2 = pk2(p1[12], p1[13]);
      unsigned c3 = pk2(p1[10], p1[11]), d3 = pk2(p1[14], p1[15]);
      PLSWAP(c0, d0); PLSWAP(c1, d1); PLSWAP(c2, d2); PLSWAP(c3, d3);
      uint4 w2 = {c0, c1, d0, d1};
      uint4 w3 = {c2, c3, d2, d3};
      pa[2] = __builtin_bit_cast(bf16x8, w2);
      pa[3] = __builtin_bit_cast(bf16x8, w3);
    }

    // O^T += V^T P^T : lane holds col q, d-rows in regs
    __builtin_amdgcn_s_setprio(1);
    {
      int row = q;  // sub 0: d rows 0..31
      int sw = (row & 7) << 4;
#pragma unroll
      for (int ks = 0; ks < 4; ks++) {
        bf16x8 vf = *(const bf16x8*)(Vc + ((row * 128 + ks * 32 + hi * 16) ^ sw));
        o0 = MFMA32(vf, pa[ks], o0);
      }
      row = 32 + q;  // sub 1: d rows 32..63
      sw = (row & 7) << 4;
#pragma unroll
      for (int ks = 0; ks < 4; ks++) {
        bf16x8 vf = *(const bf16x8*)(Vc + ((row * 128 + ks * 32 + hi * 16) ^ sw));
        o1 = MFMA32(vf, pa[ks], o1);
      }
    }
    __builtin_amdgcn_s_setprio(0);
    cur ^= 1;
  }

  // epilogue: quirk scale 1/sqrt(512) AFTER softmax; O^T -> row-major out
  float fac = 0.044194173824159216f / l_run;
  long qrow = rowbase + q0 + w * 32 + q;
  bf16* op = attn_out + qrow * 512 + h * 64;
#pragma unroll
  for (int t = 0; t < 4; t++) {
    bf16x4 v0, v1;
#pragma unroll
    for (int u = 0; u < 4; u++) {
      v0[u] = (bf16)(o0[4 * t + u] * fac);
      v1[u] = (bf16)(o1[4 * t + u] * fac);
    }
    *(bf16x4*)(op + 8 * t + 4 * hi) = v0;
    *(bf16x4*)(op + 32 + 8 * t + 4 * hi) = v1;
  }
}

// ---------------------------------------------------------------------------
// ln = LayerNorm(seq_f32 + attn_bf16) * gamma + beta   (one block per row)
__global__ __launch_bounds__(256) void ln_kernel(const float* __restrict__ seq,
                                                 const bf16* __restrict__ attn,
                                                 const float* __restrict__ gamma,
                                                 const float* __restrict__ beta,
                                                 bf16* __restrict__ out) {
  int row = blockIdx.x;
  int tid = threadIdx.x;
  long base = (long)row * 512;
  float x0 = seq[base + tid] + (float)attn[base + tid];
  float x1 = seq[base + 256 + tid] + (float)attn[base + 256 + tid];
  float s = x0 + x1, ss = x0 * x0 + x1 * x1;
#pragma unroll
  for (int mm = 1; mm < 64; mm <<= 1) {
    s += __shfl_xor(s, mm);
    ss += __shfl_xor(ss, mm);
  }
  __shared__ float red[8];
  int w = tid >> 6, l = tid & 63;
  if (l == 0) { red[w] = s; red[4 + w] = ss; }
  __syncthreads();
  s = red[0] + red[1] + red[2] + red[3];
  ss = red[4] + red[5] + red[6] + red[7];
  float mu = s * (1.f / 512.f);
  float var = ss * (1.f / 512.f) - mu * mu;
  float rs = rsqrtf(var + 1e-5f);
  out[base + tid] = (bf16)((x0 - mu) * rs * gamma[tid] + beta[tid]);
  out[base + 256 + tid] = (bf16)((x1 - mu) * rs * gamma[tid + 256] + beta[tid + 256]);
}

// ---------------------------------------------------------------------------
extern "C" void kernel_launch(void* const* d_in, const int* in_sizes, int n_in,
                              void* d_out, int out_size, void* d_ws, size_t ws_size,
                              hipStream_t stream) {
  const float* seq = (const float*)d_in[0];
  const float* Wq = (const float*)d_in[1];
  const float* bq = (const float*)d_in[2];
  const float* Wk = (const float*)d_in[3];
  const float* bk = (const float*)d_in[4];
  const float* Wv = (const float*)d_in[5];
  const float* bv = (const float*)d_in[6];
  const float* W1 = (const float*)d_in[7];
  const float* b1 = (const float*)d_in[8];
  const float* W2 = (const float*)d_in[9];
  const float* b2 = (const float*)d_in[10];
  const float* gamma = (const float*)d_in[11];
  const float* beta = (const float*)d_in[12];
  float* out = (float*)d_out;  // reference output dtype is float32

  // workspace layout (bytes)
  char* ws = (char*)d_ws;
  if (ws_size < 89659392u) return;  // loud failure signature if ws too small
  bf16* seq_bf = (bf16*)(ws + 0);          //  8192x512   bf16  (8,388,608)
  bf16* qkvT = (bf16*)(ws + 8388608);      //  1536x512   bf16  (1,572,864)
  bf16* W1T = (bf16*)(ws + 9961472);       //  2048x512   bf16  (2,097,152)
  bf16* W2T = (bf16*)(ws + 12058624);      //  512x2048   bf16  (2,097,152)
  float* bqkv = (float*)(ws + 14155776);   //  1536       f32   (6,144)
  bf16* QKV = (bf16*)(ws + 14161920);      //  8192x1536  bf16  (25,165,824; V third unused)
  bf16* attn = (bf16*)(ws + 39327744);     //  8192x512   bf16  (8,388,608)
  bf16* ln = (bf16*)(ws + 47716352);       //  8192x512   bf16  (8,388,608)
  bf16* hidden = (bf16*)(ws + 56104960);   //  8192x2048  bf16  (33,554,432)
  bf16* vt = (bf16*)(ws + 56104960);       //  64x64x1024 bf16  (8.4MB, aliases hidden:
                                           //  written by QKV gemm, read by attn,
                                           //  dead before FFN1 overwrites hidden)

  // single fused pre-pass launch (replaces 5 serialized small launches)
  prep_kernel<<<4870, 256, 0, stream>>>(seq, Wq, Wk, Wv, W1, W2, bq, bk, bv,
                                        seq_bf, qkvT, W1T, W2T, bqkv);

  // QKV = seq_bf @ [Wq|Wk|Wv] + bias : M=8192 N=1536 K=512
  // Q,K cols -> QKV row-major; V cols -> vt[b*8+h][d][s] (transposed, fused)
  gemm_bt<0, 0, 1, bf16><<<dim3(12, 64), 256, 0, stream>>>(
      seq_bf, qkvT, bqkv, (const bf16*)nullptr, QKV, vt, 512, 512, 512, 1536);
  attn_fwd<<<dim3(8, 8, 8), 256, 0, stream>>>(QKV, vt, attn);
  ln_kernel<<<8192, 256, 0, stream>>>(seq, attn, gamma, beta, ln);
  // hidden = leaky_relu(ln @ W1 + b1) : M=8192 N=2048 K=512  (overwrites vt, OK)
  gemm_bt<1, 0, 0, bf16><<<dim3(16, 64), 256, 0, stream>>>(
      ln, W1T, b1, (const bf16*)nullptr, hidden, (bf16*)nullptr, 512, 512, 512, 2048);
  // out = ln + hidden @ W2 + b2 : M=8192 N=512 K=2048
  gemm_bt<0, 1, 0, float><<<dim3(4, 64), 256, 0, stream>>>(
      hidden, W2T, b2, ln, out, (bf16*)nullptr, 2048, 2048, 2048, 512);
}

// Round 13
// 134.213 us; speedup vs baseline: 1.3957x; 1.0722x over previous
//
#include <hip/hip_runtime.h>

typedef __bf16 bf16;
typedef __bf16 bf16x4 __attribute__((ext_vector_type(4)));
typedef __bf16 bf16x8 __attribute__((ext_vector_type(8)));
typedef float f32x4 __attribute__((ext_vector_type(4)));
typedef float f32x16 __attribute__((ext_vector_type(16)));

#define MFMA16(a, b, c) __builtin_amdgcn_mfma_f32_16x16x32_bf16((a), (b), (c), 0, 0, 0)
#define MFMA32(a, b, c) __builtin_amdgcn_mfma_f32_32x32x16_bf16((a), (b), (c), 0, 0, 0)
// swap vdst's high 32 lanes with vsrc's low 32 lanes (both regs updated).
// ONLY safe when a and b hold distinct values (else regalloc may coalesce
// them into one VGPR and the swap degenerates) -- R6 post-mortem.
#define PLSWAP(a, b) asm("v_permlane32_swap_b32 %0, %1" : "+v"(a), "+v"(b))

// async global->LDS, 16B per lane. Dest must be linear in lane order (HW uses
// wave-uniform base + lane*16); swizzle is applied to the SOURCE address.
typedef const void __attribute__((address_space(1)))* gas1;
typedef void __attribute__((address_space(3)))* las3;
#define ASYNC16(g, l) __builtin_amdgcn_global_load_lds((gas1)(g), (las3)(l), 16, 0, 0)

__device__ __forceinline__ unsigned pk2(float lo, float hi) {
  unsigned short a = __builtin_bit_cast(unsigned short, (bf16)lo);
  unsigned short b = __builtin_bit_cast(unsigned short, (bf16)hi);
  return (unsigned)a | ((unsigned)b << 16);
}

// ---------------------------------------------------------------------------
// Fused pre-pass: one launch replaces {cvt, Wq/Wk/Wv transpose, W1T, W2T,
// concat_bias}. Block-id ranges select the sub-task; branches are
// block-uniform; barriers only inside transpose ranges (per-block, legal).
__global__ __launch_bounds__(256) void prep_kernel(
    const float* __restrict__ seq, const float* __restrict__ Wq,
    const float* __restrict__ Wk, const float* __restrict__ Wv,
    const float* __restrict__ W1, const float* __restrict__ W2,
    const float* __restrict__ bq, const float* __restrict__ bk,
    const float* __restrict__ bv, bf16* __restrict__ seq_bf,
    bf16* __restrict__ qkvT, bf16* __restrict__ W1T, bf16* __restrict__ W2T,
    float* __restrict__ bqkv) {
  __shared__ float tile[32][33];
  const int blk = blockIdx.x;
  const int tid = threadIdx.x;

  if (blk < 2048) {  // cvt f32->bf16
    int i = blk * 256 + tid;
    float4 a = ((const float4*)seq)[2 * i];
    float4 b = ((const float4*)seq)[2 * i + 1];
    bf16x8 v;
    v[0] = (bf16)a.x; v[1] = (bf16)a.y; v[2] = (bf16)a.z; v[3] = (bf16)a.w;
    v[4] = (bf16)b.x; v[5] = (bf16)b.y; v[6] = (bf16)b.z; v[7] = (bf16)b.w;
    ((bf16x8*)seq_bf)[i] = v;
    return;
  }

  const int tx = tid & 31, ty = tid >> 5;  // (32,8) remap for transposes
  const float* in;
  bf16* out;
  int N, K, bx, by;
  if (blk < 3840) {
    if (blk < 2816) {  // Wq/Wk/Wv: 256 blocks each, N=K=512
      int t = blk - 2048;
      int which = t >> 8;
      int r = t & 255;
      in = which == 0 ? Wq : (which == 1 ? Wk : Wv);
      out = qkvT + (long)which * 512 * 512;
      N = 512; K = 512;
      bx = r & 15; by = r >> 4;
    } else {  // W1: N=2048, K=512, grid (64,16)
      int t = blk - 2816;
      in = W1; out = W1T; N = 2048; K = 512;
      bx = t & 63; by = t >> 6;
    }
  } else if (blk < 4864) {  // W2: N=512, K=2048, grid (16,64)
    int t = blk - 3840;
    in = W2; out = W2T; N = 512; K = 2048;
    bx = t & 15; by = t >> 4;
  } else {  // concat bias
    int i = (blk - 4864) * 256 + tid;
    if (i < 512) bqkv[i] = bq[i];
    else if (i < 1024) bqkv[i] = bk[i - 512];
    else if (i < 1536) bqkv[i] = bv[i - 1024];
    return;
  }

  int n0 = bx * 32, k0 = by * 32;
#pragma unroll
  for (int i = 0; i < 4; i++) tile[ty + i * 8][tx] = in[(long)(k0 + ty + i * 8) * N + n0 + tx];
  __syncthreads();
#pragma unroll
  for (int i = 0; i < 4; i++)
    out[(long)(n0 + ty + i * 8) * K + k0 + tx] = (bf16)tile[tx][ty + i * 8];
}

// ---------------------------------------------------------------------------
// C[M,N](OutT) = act(A[M,K](bf16) @ BT[N,K](bf16)^T + bias) [+ resid]
// 128x128 tile, BK=64, 4 waves (2x2, 64x64/wave = m97 FLOP/LDS-byte ratio),
// 16x16x32 MFMA. global_load_lds staging: linear LDS dest, XOR-swizzled
// (involution) source, swizzled reads (rule #21). R5-proven structure.
// 1-D grid + bijective XCD-chunk swizzle (T1; requires nwg%8==0): blocks
// sharing an A row-panel land on one XCD -> panel is L2-resident.
// VSPLIT: blocks with bcol>=1024 write the V third transposed into
// vt[b*8+h][d][s] instead of C (feeds attention without a transpose pass).
template <int ACT, int RESID, int VSPLIT, typename OutT>
__global__ __launch_bounds__(256, 2)
void gemm_bt(const bf16* __restrict__ A, const bf16* __restrict__ BT,
             const float* __restrict__ bias, const bf16* __restrict__ resid,
             OutT* __restrict__ C, bf16* __restrict__ vt,
             int K, int lda, int ldb, int ldc, int gx) {
  __shared__ __align__(16) char As[128 * 128];  // 128 rows x 64 bf16 (128B/row)
  __shared__ __align__(16) char Bs[128 * 128];
  const int tid = threadIdx.x;
  const int l = tid & 63, w = tid >> 6;
  const int lrow = l & 15, lhi = l >> 4;
  const int wr = w >> 1, wc = w & 1;
  // XCD swizzle: XCD(bid)=bid%8; give each XCD a contiguous work-id chunk
  const int bid = blockIdx.x;
  const int nwg = gridDim.x;  // multiple of 8 (768 / 1024 / 256)
  const int wg = (bid & 7) * (nwg >> 3) + (bid >> 3);
  const long brow = (long)(wg / gx) * 128;
  const long bcol = (long)(wg % gx) * 128;

  f32x4 zero = {0.f, 0.f, 0.f, 0.f};
  f32x4 acc[4][4];
#pragma unroll
  for (int m = 0; m < 4; m++)
#pragma unroll
    for (int n = 0; n < 4; n++) acc[m][n] = zero;

  for (int kt = 0; kt < K; kt += 64) {
    __syncthreads();
#pragma unroll
    for (int c = 0; c < 4; c++) {
      int idx = c * 256 + tid;                    // 16B chunk id (lane-consecutive)
      int row = idx >> 3;                          // 8 chunks per 128B row
      int cole = ((idx & 7) ^ (row & 7)) * 8;      // swizzled source column
      ASYNC16(A + (brow + row) * lda + kt + cole, As + idx * 16);
      ASYNC16(BT + (bcol + row) * ldb + kt + cole, Bs + idx * 16);
    }
    __syncthreads();  // compiler drains vmcnt before s_barrier
    bf16x8 af[4][2], bfr[4][2];
#pragma unroll
    for (int m = 0; m < 4; m++) {
      int row = wr * 64 + m * 16 + lrow;
      int base = row * 128 + lhi * 16;
      int sw = (row & 7) << 4;
      af[m][0] = *(const bf16x8*)(As + (base ^ sw));
      af[m][1] = *(const bf16x8*)(As + ((base + 64) ^ sw));
    }
#pragma unroll
    for (int n = 0; n < 4; n++) {
      int row = wc * 64 + n * 16 + lrow;
      int base = row * 128 + lhi * 16;
      int sw = (row & 7) << 4;
      bfr[n][0] = *(const bf16x8*)(Bs + (base ^ sw));
      bfr[n][1] = *(const bf16x8*)(Bs + ((base + 64) ^ sw));
    }
#pragma unroll
    for (int m = 0; m < 4; m++)
#pragma unroll
      for (int n = 0; n < 4; n++) {
        acc[m][n] = MFMA16(af[m][0], bfr[n][0], acc[m][n]);
        acc[m][n] = MFMA16(af[m][1], bfr[n][1], acc[m][n]);
      }
  }

  if (VSPLIT && bcol >= 1024) {
    // V third -> vt[b*8+h][d][s]; rows brow.. are b*1024+s, cols are 1024+h*64+d
#pragma unroll
    for (int m = 0; m < 4; m++) {
#pragma unroll
      for (int n = 0; n < 4; n++) {
        long col = bcol + wc * 64 + n * 16 + lrow;
        float bv = bias[col];
        int cc = (int)col - 1024;
        int hh = cc >> 6, dd = cc & 63;
        long row0 = brow + wr * 64 + m * 16 + lhi * 4;
        int b = (int)(row0 >> 10), s0 = (int)(row0 & 1023);
        bf16x4 v4;
#pragma unroll
        for (int r = 0; r < 4; r++) v4[r] = (bf16)(acc[m][n][r] + bv);
        *(bf16x4*)(vt + ((long)(b * 8 + hh) * 64 + dd) * 1024 + s0) = v4;
      }
    }
    return;
  }

#pragma unroll
  for (int m = 0; m < 4; m++) {
#pragma unroll
    for (int n = 0; n < 4; n++) {
      long col = bcol + wc * 64 + n * 16 + lrow;
      float bv = bias[col];
#pragma unroll
      for (int r = 0; r < 4; r++) {
        long row = brow + wr * 64 + m * 16 + lhi * 4 + r;
        float v = acc[m][n][r] + bv;
        if (ACT) v = v > 0.f ? v : 0.01f * v;
        if (RESID) v += (float)resid[row * ldc + col];
        C[row * ldc + col] = (OutT)v;
      }
    }
  }
}

// ---------------------------------------------------------------------------
// Flash attention, swapped-operand 32x32x16 structure (T12) -- R8-proven
// math, XCD-affine grid: dims are (h, b, qx) so linear id = h + 8b + 64qx
// and XCD = id%8 = h. All q-blocks/batches of head h share one XCD; per-XCD
// K/V working set = 8 batches x 256KB = 2MB <= 4MB L2 (R11 proved residency:
// FETCH 73.8 -> 17MB). Counted-vmcnt K/V dbuf; softmax in-register; P repack
// via pk-casts + distinct-value PLSWAPs. Quirk: softmax FIRST, then /sqrt(512).
// 4 waves, wave owns 32 q-rows; KVBLK=64.
__global__ __launch_bounds__(256, 2)
void attn_fwd(const bf16* __restrict__ QKV, const bf16* __restrict__ Vtg,
              bf16* __restrict__ attn_out) {
  __shared__ __align__(16) char Ks[2][64 * 128];  // [key][d] swizzled, dbuf
  __shared__ __align__(16) char Vs[2][64 * 128];  // [d][s] swizzled, dbuf
  const int tid = threadIdx.x;
  const int l = tid & 63, w = tid >> 6;
  const int q = l & 31, hi = l >> 5;
  const int h = blockIdx.x;                        // XCD = h
  const long rowbase = (long)blockIdx.y * 1024;    // batch b
  const int q0 = blockIdx.z * 128;                 // q-tile
  const float LOG2E = 1.4426950408889634f;

  const bf16* Kb = QKV + 512;
  const bf16* Vb = Vtg + ((long)blockIdx.y * 8 + h) * 64 * 1024;  // [64][1024]

  auto stage = [&](int buf, int kt) {
#pragma unroll
    for (int c = 0; c < 2; c++) {
      int idx = c * 256 + tid;
      int row = idx >> 3;
      int cole = ((idx & 7) ^ (row & 7)) * 8;
      ASYNC16(Kb + (rowbase + kt * 64 + row) * 1536 + h * 64 + cole, Ks[buf] + idx * 16);
      ASYNC16(Vb + row * 1024 + kt * 64 + cole, Vs[buf] + idx * 16);
    }
  };

  // Q fragments (B-operand): aq[sd][j] = Q[qrow][sd*16 + hi*8 + j]
  bf16x8 aq[4];
  {
    long qrow = rowbase + q0 + w * 32 + q;
    const bf16* p = QKV + qrow * 1536 + h * 64 + hi * 8;
    aq[0] = *(const bf16x8*)(p);
    aq[1] = *(const bf16x8*)(p + 16);
    aq[2] = *(const bf16x8*)(p + 32);
    aq[3] = *(const bf16x8*)(p + 48);
  }
  // pin Q loads complete BEFORE the pipeline starts, so the compiler's
  // load-use waitcnt can't drain the prefetch queue inside the loop
  asm volatile("" ::"v"(aq[0]), "v"(aq[1]), "v"(aq[2]), "v"(aq[3]));

  f32x16 o0, o1;
#pragma unroll
  for (int i = 0; i < 16; i++) { o0[i] = 0.f; o1[i] = 0.f; }
  float m_run = -1e30f, l_run = 0.f;

  stage(0, 0);
  int cur = 0;

  for (int kt = 0; kt < 16; ++kt) {
    // barrier A: all waves done READING buf cur^1 -> safe to overwrite
    asm volatile("" ::: "memory");
    __builtin_amdgcn_s_barrier();
    asm volatile("" ::: "memory");
    stage(cur ^ 1, (kt + 1) & 15);
    asm volatile("s_waitcnt vmcnt(4)" ::: "memory");  // older 4 (tile kt) landed
    __builtin_amdgcn_sched_barrier(0);
    __builtin_amdgcn_s_barrier();  // barrier B
    asm volatile("" ::: "memory");

    const char* Kc = Ks[cur];
    const char* Vc = Vs[cur];

    // S^T = K Q^T : lane holds col q=l&31, 32 keys across regs/halves
    f32x16 s0, s1;
#pragma unroll
    for (int i = 0; i < 16; i++) { s0[i] = 0.f; s1[i] = 0.f; }
    __builtin_amdgcn_s_setprio(1);
#pragma unroll
    for (int t = 0; t < 2; t++) {
      f32x16 c;
#pragma unroll
      for (int i = 0; i < 16; i++) c[i] = 0.f;
      int row = t * 32 + q;
      int sw = (row & 7) << 4;
#pragma unroll
      for (int sd = 0; sd < 4; sd++) {
        bf16x8 kf = *(const bf16x8*)(Kc + ((row * 128 + sd * 32 + hi * 16) ^ sw));
        c = MFMA32(kf, aq[sd], c);
      }
      if (t) s1 = c; else s0 = c;
    }
    __builtin_amdgcn_s_setprio(0);

    // in-register online softmax (lane owns q-row; halves share via 1 shfl)
    float tmax = s0[0];
#pragma unroll
    for (int i = 1; i < 16; i++) tmax = fmaxf(tmax, s0[i]);
#pragma unroll
    for (int i = 0; i < 16; i++) tmax = fmaxf(tmax, s1[i]);
    tmax = fmaxf(tmax, __shfl_xor(tmax, 32));
    float mn = fmaxf(m_run, tmax);
    float al = __builtin_exp2f((m_run - mn) * LOG2E);
    float mh = mn * LOG2E;
    m_run = mn;
    float p0[16], p1[16];
    float ps = 0.f;
#pragma unroll
    for (int i = 0; i < 16; i++) {
      p0[i] = __builtin_exp2f(__builtin_fmaf(s0[i], LOG2E, -mh));
      ps += p0[i];
    }
#pragma unroll
    for (int i = 0; i < 16; i++) {
      p1[i] = __builtin_exp2f(__builtin_fmaf(s1[i], LOG2E, -mh));
      ps += p1[i];
    }
    ps += __shfl_xor(ps, 32);
    l_run = l_run * al + ps;
#pragma unroll
    for (int i = 0; i < 16; i++) { o0[i] *= al; o1[i] *= al; }

    // repack P (C-layout) -> 4 B-fragments pa[ks] (k = ks*16 + hi*8 + j)
    bf16x8 pa[4];
    {
      unsigned a0 = pk2(p0[0], p0[1]), b0 = pk2(p0[4], p0[5]);
      unsigned a1 = pk2(p0[2], p0[3]), b1 = pk2(p0[6], p0[7]);
      unsigned a2 = pk2(p0[8], p0[9]), b2 = pk2(p0[12], p0[13]);
      unsigned a3 = pk2(p0[10], p0[11]), b3 = pk2(p0[14], p0[15]);
      PLSWAP(a0, b0); PLSWAP(a1, b1); PLSWAP(a2, b2); PLSWAP(a3, b3);
      uint4 w0 = {a0, a1, b0, b1};
      uint4 w1 = {a2, a3, b2, b3};
      pa[0] = __builtin_bit_cast(bf16x8, w0);
      pa[1] = __builtin_bit_cast(bf16x8, w1);
      unsigned c0 = pk2(p1[0], p1[1]), d0 = pk2(p1[4], p1[5]);
      unsigned c1 = pk2(p1[2], p1[3]), d1 = pk2(p1[6], p1[7]);
      unsigned c2 = pk2(p1[8], p1[9]), d2 = pk2(p1[12], p1[13]);
      unsigned c3 = pk2(p1[10], p1[11]), d3 = pk2(p1[14], p1[15]);
      PLSWAP(c0, d0); PLSWAP(c1, d1); PLSWAP(c2, d2); PLSWAP(c3, d3);
      uint4 w2 = {c0, c1, d0, d1};
      uint4 w3 = {c2, c3, d2, d3};
      pa[2] = __builtin_bit_cast(bf16x8, w2);
      pa[3] = __builtin_bit_cast(bf16x8, w3);
    }

    // O^T += V^T P^T : lane holds col q, d-rows in regs
    __builtin_amdgcn_s_setprio(1);
    {
      int row = q;  // sub 0: d rows 0..31
      int sw = (row & 7) << 4;
#pragma unroll
      for (int ks = 0; ks < 4; ks++) {
        bf16x8 vf = *(const bf16x8*)(Vc + ((row * 128 + ks * 32 + hi * 16) ^ sw));
        o0 = MFMA32(vf, pa[ks], o0);
      }
      row = 32 + q;  // sub 1: d rows 32..63
      sw = (row & 7) << 4;
#pragma unroll
      for (int ks = 0; ks < 4; ks++) {
        bf16x8 vf = *(const bf16x8*)(Vc + ((row * 128 + ks * 32 + hi * 16) ^ sw));
        o1 = MFMA32(vf, pa[ks], o1);
      }
    }
    __builtin_amdgcn_s_setprio(0);
    cur ^= 1;
  }

  // epilogue: quirk scale 1/sqrt(512) AFTER softmax; O^T -> row-major out
  float fac = 0.044194173824159216f / l_run;
  long qrow = rowbase + q0 + w * 32 + q;
  bf16* op = attn_out + qrow * 512 + h * 64;
#pragma unroll
  for (int t = 0; t < 4; t++) {
    bf16x4 v0, v1;
#pragma unroll
    for (int u = 0; u < 4; u++) {
      v0[u] = (bf16)(o0[4 * t + u] * fac);
      v1[u] = (bf16)(o1[4 * t + u] * fac);
    }
    *(bf16x4*)(op + 8 * t + 4 * hi) = v0;
    *(bf16x4*)(op + 32 + 8 * t + 4 * hi) = v1;
  }
}

// ---------------------------------------------------------------------------
// ln = LayerNorm(seq_f32 + attn_bf16) * gamma + beta   (one block per row)
__global__ __launch_bounds__(256) void ln_kernel(const float* __restrict__ seq,
                                                 const bf16* __restrict__ attn,
                                                 const float* __restrict__ gamma,
                                                 const float* __restrict__ beta,
                                                 bf16* __restrict__ out) {
  int row = blockIdx.x;
  int tid = threadIdx.x;
  long base = (long)row * 512;
  float x0 = seq[base + tid] + (float)attn[base + tid];
  float x1 = seq[base + 256 + tid] + (float)attn[base + 256 + tid];
  float s = x0 + x1, ss = x0 * x0 + x1 * x1;
#pragma unroll
  for (int mm = 1; mm < 64; mm <<= 1) {
    s += __shfl_xor(s, mm);
    ss += __shfl_xor(ss, mm);
  }
  __shared__ float red[8];
  int w = tid >> 6, l = tid & 63;
  if (l == 0) { red[w] = s; red[4 + w] = ss; }
  __syncthreads();
  s = red[0] + red[1] + red[2] + red[3];
  ss = red[4] + red[5] + red[6] + red[7];
  float mu = s * (1.f / 512.f);
  float var = ss * (1.f / 512.f) - mu * mu;
  float rs = rsqrtf(var + 1e-5f);
  out[base + tid] = (bf16)((x0 - mu) * rs * gamma[tid] + beta[tid]);
  out[base + 256 + tid] = (bf16)((x1 - mu) * rs * gamma[tid + 256] + beta[tid + 256]);
}

// ---------------------------------------------------------------------------
extern "C" void kernel_launch(void* const* d_in, const int* in_sizes, int n_in,
                              void* d_out, int out_size, void* d_ws, size_t ws_size,
                              hipStream_t stream) {
  const float* seq = (const float*)d_in[0];
  const float* Wq = (const float*)d_in[1];
  const float* bq = (const float*)d_in[2];
  const float* Wk = (const float*)d_in[3];
  const float* bk = (const float*)d_in[4];
  const float* Wv = (const float*)d_in[5];
  const float* bv = (const float*)d_in[6];
  const float* W1 = (const float*)d_in[7];
  const float* b1 = (const float*)d_in[8];
  const float* W2 = (const float*)d_in[9];
  const float* b2 = (const float*)d_in[10];
  const float* gamma = (const float*)d_in[11];
  const float* beta = (const float*)d_in[12];
  float* out = (float*)d_out;  // reference output dtype is float32

  // workspace layout (bytes)
  char* ws = (char*)d_ws;
  if (ws_size < 89659392u) return;  // loud failure signature if ws too small
  bf16* seq_bf = (bf16*)(ws + 0);          //  8192x512   bf16  (8,388,608)
  bf16* qkvT = (bf16*)(ws + 8388608);      //  1536x512   bf16  (1,572,864)
  bf16* W1T = (bf16*)(ws + 9961472);       //  2048x512   bf16  (2,097,152)
  bf16* W2T = (bf16*)(ws + 12058624);      //  512x2048   bf16  (2,097,152)
  float* bqkv = (float*)(ws + 14155776);   //  1536       f32   (6,144)
  bf16* QKV = (bf16*)(ws + 14161920);      //  8192x1536  bf16  (25,165,824; V third unused)
  bf16* attn = (bf16*)(ws + 39327744);     //  8192x512   bf16  (8,388,608)
  bf16* ln = (bf16*)(ws + 47716352);       //  8192x512   bf16  (8,388,608)
  bf16* hidden = (bf16*)(ws + 56104960);   //  8192x2048  bf16  (33,554,432)
  bf16* vt = (bf16*)(ws + 56104960);       //  64x64x1024 bf16  (8.4MB, aliases hidden:
                                           //  written by QKV gemm, read by attn,
                                           //  dead before FFN1 overwrites hidden)

  // single fused pre-pass launch (replaces 5 serialized small launches)
  prep_kernel<<<4870, 256, 0, stream>>>(seq, Wq, Wk, Wv, W1, W2, bq, bk, bv,
                                        seq_bf, qkvT, W1T, W2T, bqkv);

  // QKV = seq_bf @ [Wq|Wk|Wv] + bias : M=8192 N=1536 K=512 (768 blocks, %8==0)
  // Q,K cols -> QKV row-major; V cols -> vt[b*8+h][d][s] (transposed, fused)
  gemm_bt<0, 0, 1, bf16><<<768, 256, 0, stream>>>(
      seq_bf, qkvT, bqkv, (const bf16*)nullptr, QKV, vt, 512, 512, 512, 1536, 12);
  // grid (h, b, qx): XCD = linear%8 = h -> per-XCD K/V set 2MB, L2-resident
  attn_fwd<<<dim3(8, 8, 8), 256, 0, stream>>>(QKV, vt, attn);
  ln_kernel<<<8192, 256, 0, stream>>>(seq, attn, gamma, beta, ln);
  // hidden = leaky_relu(ln @ W1 + b1) : M=8192 N=2048 K=512 (1024 blocks)
  gemm_bt<1, 0, 0, bf16><<<1024, 256, 0, stream>>>(
      ln, W1T, b1, (const bf16*)nullptr, hidden, (bf16*)nullptr, 512, 512, 512, 2048, 16);
  // out = ln + hidden @ W2 + b2 : M=8192 N=512 K=2048 (256 blocks)
  gemm_bt<0, 1, 0, float><<<256, 256, 0, stream>>>(
      hidden, W2T, b2, ln, out, (bf16*)nullptr, 2048, 2048, 2048, 512, 4);
}

// Round 14
// 130.751 us; speedup vs baseline: 1.4327x; 1.0265x over previous
//
#include <hip/hip_runtime.h>

typedef __bf16 bf16;
typedef __bf16 bf16x4 __attribute__((ext_vector_type(4)));
typedef __bf16 bf16x8 __attribute__((ext_vector_type(8)));
typedef float f32x4 __attribute__((ext_vector_type(4)));
typedef float f32x16 __attribute__((ext_vector_type(16)));

#define MFMA16(a, b, c) __builtin_amdgcn_mfma_f32_16x16x32_bf16((a), (b), (c), 0, 0, 0)
#define MFMA32(a, b, c) __builtin_amdgcn_mfma_f32_32x32x16_bf16((a), (b), (c), 0, 0, 0)
// swap vdst's high 32 lanes with vsrc's low 32 lanes (both regs updated).
// ONLY safe when a and b hold distinct values (else regalloc may coalesce
// them into one VGPR and the swap degenerates) -- R6 post-mortem.
#define PLSWAP(a, b) asm("v_permlane32_swap_b32 %0, %1" : "+v"(a), "+v"(b))

// async global->LDS, 16B per lane. Dest must be linear in lane order (HW uses
// wave-uniform base + lane*16); swizzle is applied to the SOURCE address.
typedef const void __attribute__((address_space(1)))* gas1;
typedef void __attribute__((address_space(3)))* las3;
#define ASYNC16(g, l) __builtin_amdgcn_global_load_lds((gas1)(g), (las3)(l), 16, 0, 0)

__device__ __forceinline__ unsigned pk2(float lo, float hi) {
  unsigned short a = __builtin_bit_cast(unsigned short, (bf16)lo);
  unsigned short b = __builtin_bit_cast(unsigned short, (bf16)hi);
  return (unsigned)a | ((unsigned)b << 16);
}

// ---------------------------------------------------------------------------
// Fused pre-pass: one launch replaces {cvt, Wq/Wk/Wv transpose, W1T, W2T,
// concat_bias}. Block-id ranges select the sub-task; branches are
// block-uniform; barriers only inside transpose ranges (per-block, legal).
__global__ __launch_bounds__(256) void prep_kernel(
    const float* __restrict__ seq, const float* __restrict__ Wq,
    const float* __restrict__ Wk, const float* __restrict__ Wv,
    const float* __restrict__ W1, const float* __restrict__ W2,
    const float* __restrict__ bq, const float* __restrict__ bk,
    const float* __restrict__ bv, bf16* __restrict__ seq_bf,
    bf16* __restrict__ qkvT, bf16* __restrict__ W1T, bf16* __restrict__ W2T,
    float* __restrict__ bqkv) {
  __shared__ float tile[32][33];
  const int blk = blockIdx.x;
  const int tid = threadIdx.x;

  if (blk < 2048) {  // cvt f32->bf16
    int i = blk * 256 + tid;
    float4 a = ((const float4*)seq)[2 * i];
    float4 b = ((const float4*)seq)[2 * i + 1];
    bf16x8 v;
    v[0] = (bf16)a.x; v[1] = (bf16)a.y; v[2] = (bf16)a.z; v[3] = (bf16)a.w;
    v[4] = (bf16)b.x; v[5] = (bf16)b.y; v[6] = (bf16)b.z; v[7] = (bf16)b.w;
    ((bf16x8*)seq_bf)[i] = v;
    return;
  }

  const int tx = tid & 31, ty = tid >> 5;  // (32,8) remap for transposes
  const float* in;
  bf16* out;
  int N, K, bx, by;
  if (blk < 3840) {
    if (blk < 2816) {  // Wq/Wk/Wv: 256 blocks each, N=K=512
      int t = blk - 2048;
      int which = t >> 8;
      int r = t & 255;
      in = which == 0 ? Wq : (which == 1 ? Wk : Wv);
      out = qkvT + (long)which * 512 * 512;
      N = 512; K = 512;
      bx = r & 15; by = r >> 4;
    } else {  // W1: N=2048, K=512, grid (64,16)
      int t = blk - 2816;
      in = W1; out = W1T; N = 2048; K = 512;
      bx = t & 63; by = t >> 6;
    }
  } else if (blk < 4864) {  // W2: N=512, K=2048, grid (16,64)
    int t = blk - 3840;
    in = W2; out = W2T; N = 512; K = 2048;
    bx = t & 15; by = t >> 4;
  } else {  // concat bias
    int i = (blk - 4864) * 256 + tid;
    if (i < 512) bqkv[i] = bq[i];
    else if (i < 1024) bqkv[i] = bk[i - 512];
    else if (i < 1536) bqkv[i] = bv[i - 1024];
    return;
  }

  int n0 = bx * 32, k0 = by * 32;
#pragma unroll
  for (int i = 0; i < 4; i++) tile[ty + i * 8][tx] = in[(long)(k0 + ty + i * 8) * N + n0 + tx];
  __syncthreads();
#pragma unroll
  for (int i = 0; i < 4; i++)
    out[(long)(n0 + ty + i * 8) * K + k0 + tx] = (bf16)tile[tx][ty + i * 8];
}

// ---------------------------------------------------------------------------
// C[M,N](OutT) = act(A[M,K](bf16) @ BT[N,K](bf16)^T + bias) [+ resid]
// BM=128 x BN (template: 128 or 64) tile, BK=64, 4 waves (2x2), 16x16x32
// MFMA. global_load_lds staging: linear LDS dest, XOR-swizzled (involution)
// source, swizzled reads (rule #21). R5-proven sync structure -- BN is a
// pure parameter change (two-lane discipline). BN=64 doubles blocks for
// narrow-N long-K shapes (FFN2: 256->512 blocks, 1->2 blocks/CU).
// 1-D grid + bijective XCD-chunk swizzle (T1; requires nwg%8==0).
// VSPLIT (BN=128 only): blocks with bcol>=1024 write the V third transposed
// into vt[b*8+h][d][s] instead of C.
template <int ACT, int RESID, int VSPLIT, int BN, typename OutT>
__global__ __launch_bounds__(256, 2)
void gemm_bt(const bf16* __restrict__ A, const bf16* __restrict__ BT,
             const float* __restrict__ bias, const bf16* __restrict__ resid,
             OutT* __restrict__ C, bf16* __restrict__ vt,
             int K, int lda, int ldb, int ldc, int gx) {
  constexpr int NT = BN / 32;  // per-wave n-tiles of 16 (wc splits BN in 2)
  __shared__ __align__(16) char As[128 * 128];  // 128 rows x 64 bf16 (128B/row)
  __shared__ __align__(16) char Bs[BN * 128];
  const int tid = threadIdx.x;
  const int l = tid & 63, w = tid >> 6;
  const int lrow = l & 15, lhi = l >> 4;
  const int wr = w >> 1, wc = w & 1;
  // XCD swizzle: XCD(bid)=bid%8; give each XCD a contiguous work-id chunk
  const int bid = blockIdx.x;
  const int nwg = gridDim.x;  // multiple of 8
  const int wg = (bid & 7) * (nwg >> 3) + (bid >> 3);
  const long brow = (long)(wg / gx) * 128;
  const long bcol = (long)(wg % gx) * BN;

  f32x4 zero = {0.f, 0.f, 0.f, 0.f};
  f32x4 acc[4][NT];
#pragma unroll
  for (int m = 0; m < 4; m++)
#pragma unroll
    for (int n = 0; n < NT; n++) acc[m][n] = zero;

  for (int kt = 0; kt < K; kt += 64) {
    __syncthreads();
#pragma unroll
    for (int c = 0; c < 4; c++) {  // A: 1024 chunks (16B each)
      int idx = c * 256 + tid;
      int row = idx >> 3;
      int cole = ((idx & 7) ^ (row & 7)) * 8;
      ASYNC16(A + (brow + row) * lda + kt + cole, As + idx * 16);
    }
#pragma unroll
    for (int c = 0; c < BN / 32; c++) {  // B: BN*8 chunks
      int idx = c * 256 + tid;
      int row = idx >> 3;
      int cole = ((idx & 7) ^ (row & 7)) * 8;
      ASYNC16(BT + (bcol + row) * ldb + kt + cole, Bs + idx * 16);
    }
    __syncthreads();  // compiler drains vmcnt before s_barrier
    bf16x8 af[4][2], bfr[NT][2];
#pragma unroll
    for (int m = 0; m < 4; m++) {
      int row = wr * 64 + m * 16 + lrow;
      int base = row * 128 + lhi * 16;
      int sw = (row & 7) << 4;
      af[m][0] = *(const bf16x8*)(As + (base ^ sw));
      af[m][1] = *(const bf16x8*)(As + ((base + 64) ^ sw));
    }
#pragma unroll
    for (int n = 0; n < NT; n++) {
      int row = wc * (16 * NT) + n * 16 + lrow;
      int base = row * 128 + lhi * 16;
      int sw = (row & 7) << 4;
      bfr[n][0] = *(const bf16x8*)(Bs + (base ^ sw));
      bfr[n][1] = *(const bf16x8*)(Bs + ((base + 64) ^ sw));
    }
#pragma unroll
    for (int m = 0; m < 4; m++)
#pragma unroll
      for (int n = 0; n < NT; n++) {
        acc[m][n] = MFMA16(af[m][0], bfr[n][0], acc[m][n]);
        acc[m][n] = MFMA16(af[m][1], bfr[n][1], acc[m][n]);
      }
  }

  if (VSPLIT && bcol >= 1024) {
    // V third -> vt[b*8+h][d][s]; rows brow.. are b*1024+s, cols are 1024+h*64+d
#pragma unroll
    for (int m = 0; m < 4; m++) {
#pragma unroll
      for (int n = 0; n < NT; n++) {
        long col = bcol + wc * (16 * NT) + n * 16 + lrow;
        float bv = bias[col];
        int cc = (int)col - 1024;
        int hh = cc >> 6, dd = cc & 63;
        long row0 = brow + wr * 64 + m * 16 + lhi * 4;
        int b = (int)(row0 >> 10), s0 = (int)(row0 & 1023);
        bf16x4 v4;
#pragma unroll
        for (int r = 0; r < 4; r++) v4[r] = (bf16)(acc[m][n][r] + bv);
        *(bf16x4*)(vt + ((long)(b * 8 + hh) * 64 + dd) * 1024 + s0) = v4;
      }
    }
    return;
  }

#pragma unroll
  for (int m = 0; m < 4; m++) {
#pragma unroll
    for (int n = 0; n < NT; n++) {
      long col = bcol + wc * (16 * NT) + n * 16 + lrow;
      float bv = bias[col];
#pragma unroll
      for (int r = 0; r < 4; r++) {
        long row = brow + wr * 64 + m * 16 + lhi * 4 + r;
        float v = acc[m][n][r] + bv;
        if (ACT) v = v > 0.f ? v : 0.01f * v;
        if (RESID) v += (float)resid[row * ldc + col];
        C[row * ldc + col] = (OutT)v;
      }
    }
  }
}

// ---------------------------------------------------------------------------
// Flash attention, swapped-operand 32x32x16 structure (T12) -- R8-proven
// math, XCD-affine grid: dims are (h, b, qx) so linear id = h + 8b + 64qx
// and XCD = id%8 = h. All q-blocks/batches of head h share one XCD; per-XCD
// K/V working set = 2MB <= 4MB L2 (R13 confirmed: FETCH 73.8 -> 12.3MB).
// Counted-vmcnt K/V dbuf; softmax in-register; P repack via pk-casts +
// distinct-value PLSWAPs. Quirk: softmax FIRST, then /sqrt(512).
// 4 waves, wave owns 32 q-rows; KVBLK=64.
__global__ __launch_bounds__(256, 2)
void attn_fwd(const bf16* __restrict__ QKV, const bf16* __restrict__ Vtg,
              bf16* __restrict__ attn_out) {
  __shared__ __align__(16) char Ks[2][64 * 128];  // [key][d] swizzled, dbuf
  __shared__ __align__(16) char Vs[2][64 * 128];  // [d][s] swizzled, dbuf
  const int tid = threadIdx.x;
  const int l = tid & 63, w = tid >> 6;
  const int q = l & 31, hi = l >> 5;
  const int h = blockIdx.x;                        // XCD = h
  const long rowbase = (long)blockIdx.y * 1024;    // batch b
  const int q0 = blockIdx.z * 128;                 // q-tile
  const float LOG2E = 1.4426950408889634f;

  const bf16* Kb = QKV + 512;
  const bf16* Vb = Vtg + ((long)blockIdx.y * 8 + h) * 64 * 1024;  // [64][1024]

  auto stage = [&](int buf, int kt) {
#pragma unroll
    for (int c = 0; c < 2; c++) {
      int idx = c * 256 + tid;
      int row = idx >> 3;
      int cole = ((idx & 7) ^ (row & 7)) * 8;
      ASYNC16(Kb + (rowbase + kt * 64 + row) * 1536 + h * 64 + cole, Ks[buf] + idx * 16);
      ASYNC16(Vb + row * 1024 + kt * 64 + cole, Vs[buf] + idx * 16);
    }
  };

  // Q fragments (B-operand): aq[sd][j] = Q[qrow][sd*16 + hi*8 + j]
  bf16x8 aq[4];
  {
    long qrow = rowbase + q0 + w * 32 + q;
    const bf16* p = QKV + qrow * 1536 + h * 64 + hi * 8;
    aq[0] = *(const bf16x8*)(p);
    aq[1] = *(const bf16x8*)(p + 16);
    aq[2] = *(const bf16x8*)(p + 32);
    aq[3] = *(const bf16x8*)(p + 48);
  }
  // pin Q loads complete BEFORE the pipeline starts, so the compiler's
  // load-use waitcnt can't drain the prefetch queue inside the loop
  asm volatile("" ::"v"(aq[0]), "v"(aq[1]), "v"(aq[2]), "v"(aq[3]));

  f32x16 o0, o1;
#pragma unroll
  for (int i = 0; i < 16; i++) { o0[i] = 0.f; o1[i] = 0.f; }
  float m_run = -1e30f, l_run = 0.f;

  stage(0, 0);
  int cur = 0;

  for (int kt = 0; kt < 16; ++kt) {
    // barrier A: all waves done READING buf cur^1 -> safe to overwrite
    asm volatile("" ::: "memory");
    __builtin_amdgcn_s_barrier();
    asm volatile("" ::: "memory");
    stage(cur ^ 1, (kt + 1) & 15);
    asm volatile("s_waitcnt vmcnt(4)" ::: "memory");  // older 4 (tile kt) landed
    __builtin_amdgcn_sched_barrier(0);
    __builtin_amdgcn_s_barrier();  // barrier B
    asm volatile("" ::: "memory");

    const char* Kc = Ks[cur];
    const char* Vc = Vs[cur];

    // S^T = K Q^T : lane holds col q=l&31, 32 keys across regs/halves
    f32x16 s0, s1;
#pragma unroll
    for (int i = 0; i < 16; i++) { s0[i] = 0.f; s1[i] = 0.f; }
    __builtin_amdgcn_s_setprio(1);
#pragma unroll
    for (int t = 0; t < 2; t++) {
      f32x16 c;
#pragma unroll
      for (int i = 0; i < 16; i++) c[i] = 0.f;
      int row = t * 32 + q;
      int sw = (row & 7) << 4;
#pragma unroll
      for (int sd = 0; sd < 4; sd++) {
        bf16x8 kf = *(const bf16x8*)(Kc + ((row * 128 + sd * 32 + hi * 16) ^ sw));
        c = MFMA32(kf, aq[sd], c);
      }
      if (t) s1 = c; else s0 = c;
    }
    __builtin_amdgcn_s_setprio(0);

    // in-register online softmax (lane owns q-row; halves share via 1 shfl)
    float tmax = s0[0];
#pragma unroll
    for (int i = 1; i < 16; i++) tmax = fmaxf(tmax, s0[i]);
#pragma unroll
    for (int i = 0; i < 16; i++) tmax = fmaxf(tmax, s1[i]);
    tmax = fmaxf(tmax, __shfl_xor(tmax, 32));
    float mn = fmaxf(m_run, tmax);
    float al = __builtin_exp2f((m_run - mn) * LOG2E);
    float mh = mn * LOG2E;
    m_run = mn;
    float p0[16], p1[16];
    float ps = 0.f;
#pragma unroll
    for (int i = 0; i < 16; i++) {
      p0[i] = __builtin_exp2f(__builtin_fmaf(s0[i], LOG2E, -mh));
      ps += p0[i];
    }
#pragma unroll
    for (int i = 0; i < 16; i++) {
      p1[i] = __builtin_exp2f(__builtin_fmaf(s1[i], LOG2E, -mh));
      ps += p1[i];
    }
    ps += __shfl_xor(ps, 32);
    l_run = l_run * al + ps;
#pragma unroll
    for (int i = 0; i < 16; i++) { o0[i] *= al; o1[i] *= al; }

    // repack P (C-layout) -> 4 B-fragments pa[ks] (k = ks*16 + hi*8 + j)
    bf16x8 pa[4];
    {
      unsigned a0 = pk2(p0[0], p0[1]), b0 = pk2(p0[4], p0[5]);
      unsigned a1 = pk2(p0[2], p0[3]), b1 = pk2(p0[6], p0[7]);
      unsigned a2 = pk2(p0[8], p0[9]), b2 = pk2(p0[12], p0[13]);
      unsigned a3 = pk2(p0[10], p0[11]), b3 = pk2(p0[14], p0[15]);
      PLSWAP(a0, b0); PLSWAP(a1, b1); PLSWAP(a2, b2); PLSWAP(a3, b3);
      uint4 w0 = {a0, a1, b0, b1};
      uint4 w1 = {a2, a3, b2, b3};
      pa[0] = __builtin_bit_cast(bf16x8, w0);
      pa[1] = __builtin_bit_cast(bf16x8, w1);
      unsigned c0 = pk2(p1[0], p1[1]), d0 = pk2(p1[4], p1[5]);
      unsigned c1 = pk2(p1[2], p1[3]), d1 = pk2(p1[6], p1[7]);
      unsigned c2 = pk2(p1[8], p1[9]), d2 = pk2(p1[12], p1[13]);
      unsigned c3 = pk2(p1[10], p1[11]), d3 = pk2(p1[14], p1[15]);
      PLSWAP(c0, d0); PLSWAP(c1, d1); PLSWAP(c2, d2); PLSWAP(c3, d3);
      uint4 w2 = {c0, c1, d0, d1};
      uint4 w3 = {c2, c3, d2, d3};
      pa[2] = __builtin_bit_cast(bf16x8, w2);
      pa[3] = __builtin_bit_cast(bf16x8, w3);
    }

    // O^T += V^T P^T : lane holds col q, d-rows in regs
    __builtin_amdgcn_s_setprio(1);
    {
      int row = q;  // sub 0: d rows 0..31
      int sw = (row & 7) << 4;
#pragma unroll
      for (int ks = 0; ks < 4; ks++) {
        bf16x8 vf = *(const bf16x8*)(Vc + ((row * 128 + ks * 32 + hi * 16) ^ sw));
        o0 = MFMA32(vf, pa[ks], o0);
      }
      row = 32 + q;  // sub 1: d rows 32..63
      sw = (row & 7) << 4;
#pragma unroll
      for (int ks = 0; ks < 4; ks++) {
        bf16x8 vf = *(const bf16x8*)(Vc + ((row * 128 + ks * 32 + hi * 16) ^ sw));
        o1 = MFMA32(vf, pa[ks], o1);
      }
    }
    __builtin_amdgcn_s_setprio(0);
    cur ^= 1;
  }

  // epilogue: quirk scale 1/sqrt(512) AFTER softmax; O^T -> row-major out
  float fac = 0.044194173824159216f / l_run;
  long qrow = rowbase + q0 + w * 32 + q;
  bf16* op = attn_out + qrow * 512 + h * 64;
#pragma unroll
  for (int t = 0; t < 4; t++) {
    bf16x4 v0, v1;
#pragma unroll
    for (int u = 0; u < 4; u++) {
      v0[u] = (bf16)(o0[4 * t + u] * fac);
      v1[u] = (bf16)(o1[4 * t + u] * fac);
    }
    *(bf16x4*)(op + 8 * t + 4 * hi) = v0;
    *(bf16x4*)(op + 32 + 8 * t + 4 * hi) = v1;
  }
}

// ---------------------------------------------------------------------------
// ln = LayerNorm(seq_f32 + attn_bf16) * gamma + beta   (one block per row)
__global__ __launch_bounds__(256) void ln_kernel(const float* __restrict__ seq,
                                                 const bf16* __restrict__ attn,
                                                 const float* __restrict__ gamma,
                                                 const float* __restrict__ beta,
                                                 bf16* __restrict__ out) {
  int row = blockIdx.x;
  int tid = threadIdx.x;
  long base = (long)row * 512;
  float x0 = seq[base + tid] + (float)attn[base + tid];
  float x1 = seq[base + 256 + tid] + (float)attn[base + 256 + tid];
  float s = x0 + x1, ss = x0 * x0 + x1 * x1;
#pragma unroll
  for (int mm = 1; mm < 64; mm <<= 1) {
    s += __shfl_xor(s, mm);
    ss += __shfl_xor(ss, mm);
  }
  __shared__ float red[8];
  int w = tid >> 6, l = tid & 63;
  if (l == 0) { red[w] = s; red[4 + w] = ss; }
  __syncthreads();
  s = red[0] + red[1] + red[2] + red[3];
  ss = red[4] + red[5] + red[6] + red[7];
  float mu = s * (1.f / 512.f);
  float var = ss * (1.f / 512.f) - mu * mu;
  float rs = rsqrtf(var + 1e-5f);
  out[base + tid] = (bf16)((x0 - mu) * rs * gamma[tid] + beta[tid]);
  out[base + 256 + tid] = (bf16)((x1 - mu) * rs * gamma[tid + 256] + beta[tid + 256]);
}

// ---------------------------------------------------------------------------
extern "C" void kernel_launch(void* const* d_in, const int* in_sizes, int n_in,
                              void* d_out, int out_size, void* d_ws, size_t ws_size,
                              hipStream_t stream) {
  const float* seq = (const float*)d_in[0];
  const float* Wq = (const float*)d_in[1];
  const float* bq = (const float*)d_in[2];
  const float* Wk = (const float*)d_in[3];
  const float* bk = (const float*)d_in[4];
  const float* Wv = (const float*)d_in[5];
  const float* bv = (const float*)d_in[6];
  const float* W1 = (const float*)d_in[7];
  const float* b1 = (const float*)d_in[8];
  const float* W2 = (const float*)d_in[9];
  const float* b2 = (const float*)d_in[10];
  const float* gamma = (const float*)d_in[11];
  const float* beta = (const float*)d_in[12];
  float* out = (float*)d_out;  // reference output dtype is float32

  // workspace layout (bytes)
  char* ws = (char*)d_ws;
  if (ws_size < 89659392u) return;  // loud failure signature if ws too small
  bf16* seq_bf = (bf16*)(ws + 0);          //  8192x512   bf16  (8,388,608)
  bf16* qkvT = (bf16*)(ws + 8388608);      //  1536x512   bf16  (1,572,864)
  bf16* W1T = (bf16*)(ws + 9961472);       //  2048x512   bf16  (2,097,152)
  bf16* W2T = (bf16*)(ws + 12058624);      //  512x2048   bf16  (2,097,152)
  float* bqkv = (float*)(ws + 14155776);   //  1536       f32   (6,144)
  bf16* QKV = (bf16*)(ws + 14161920);      //  8192x1536  bf16  (25,165,824; V third unused)
  bf16* attn = (bf16*)(ws + 39327744);     //  8192x512   bf16  (8,388,608)
  bf16* ln = (bf16*)(ws + 47716352);       //  8192x512   bf16  (8,388,608)
  bf16* hidden = (bf16*)(ws + 56104960);   //  8192x2048  bf16  (33,554,432)
  bf16* vt = (bf16*)(ws + 56104960);       //  64x64x1024 bf16  (8.4MB, aliases hidden:
                                           //  written by QKV gemm, read by attn,
                                           //  dead before FFN1 overwrites hidden)

  // single fused pre-pass launch (replaces 5 serialized small launches)
  prep_kernel<<<4870, 256, 0, stream>>>(seq, Wq, Wk, Wv, W1, W2, bq, bk, bv,
                                        seq_bf, qkvT, W1T, W2T, bqkv);

  // QKV = seq_bf @ [Wq|Wk|Wv] + bias : M=8192 N=1536 K=512 (768 blocks, %8==0)
  // Q,K cols -> QKV row-major; V cols -> vt[b*8+h][d][s] (transposed, fused)
  gemm_bt<0, 0, 1, 128, bf16><<<768, 256, 0, stream>>>(
      seq_bf, qkvT, bqkv, (const bf16*)nullptr, QKV, vt, 512, 512, 512, 1536, 12);
  // grid (h, b, qx): XCD = linear%8 = h -> per-XCD K/V set 2MB, L2-resident
  attn_fwd<<<dim3(8, 8, 8), 256, 0, stream>>>(QKV, vt, attn);
  ln_kernel<<<8192, 256, 0, stream>>>(seq, attn, gamma, beta, ln);
  // hidden = leaky_relu(ln @ W1 + b1) : M=8192 N=2048 K=512 (1024 blocks)
  gemm_bt<1, 0, 0, 128, bf16><<<1024, 256, 0, stream>>>(
      ln, W1T, b1, (const bf16*)nullptr, hidden, (bf16*)nullptr, 512, 512, 512, 2048, 16);
  // out = ln + hidden @ W2 + b2 : M=8192 N=512 K=2048
  // BN=64 retile: 512 blocks = 2/CU (was 256 = 1/CU) -- drain-hiding TLP x2
  gemm_bt<0, 1, 0, 64, float><<<512, 256, 0, stream>>>(
      hidden, W2T, b2, ln, out, (bf16*)nullptr, 2048, 2048, 2048, 512, 8);
}

// Round 15
// 124.620 us; speedup vs baseline: 1.5032x; 1.0492x over previous
//
#include <hip/hip_runtime.h>

typedef __bf16 bf16;
typedef __bf16 bf16x4 __attribute__((ext_vector_type(4)));
typedef __bf16 bf16x8 __attribute__((ext_vector_type(8)));
typedef float f32x4 __attribute__((ext_vector_type(4)));
typedef float f32x16 __attribute__((ext_vector_type(16)));

#define MFMA16(a, b, c) __builtin_amdgcn_mfma_f32_16x16x32_bf16((a), (b), (c), 0, 0, 0)
#define MFMA32(a, b, c) __builtin_amdgcn_mfma_f32_32x32x16_bf16((a), (b), (c), 0, 0, 0)
// swap vdst's high 32 lanes with vsrc's low 32 lanes (both regs updated).
// ONLY safe when a and b hold distinct values (else regalloc may coalesce
// them into one VGPR and the swap degenerates) -- R6 post-mortem.
#define PLSWAP(a, b) asm("v_permlane32_swap_b32 %0, %1" : "+v"(a), "+v"(b))

// async global->LDS, 16B per lane. Dest must be linear in lane order (HW uses
// wave-uniform base + lane*16); swizzle is applied to the SOURCE address.
typedef const void __attribute__((address_space(1)))* gas1;
typedef void __attribute__((address_space(3)))* las3;
#define ASYNC16(g, l) __builtin_amdgcn_global_load_lds((gas1)(g), (las3)(l), 16, 0, 0)

__device__ __forceinline__ unsigned pk2(float lo, float hi) {
  unsigned short a = __builtin_bit_cast(unsigned short, (bf16)lo);
  unsigned short b = __builtin_bit_cast(unsigned short, (bf16)hi);
  return (unsigned)a | ((unsigned)b << 16);
}

// ---------------------------------------------------------------------------
// Fused pre-pass: one launch replaces {cvt, Wq/Wk/Wv transpose, W1T, W2T,
// concat_bias}. Block-id ranges select the sub-task; branches are
// block-uniform; barriers only inside transpose ranges (per-block, legal).
__global__ __launch_bounds__(256) void prep_kernel(
    const float* __restrict__ seq, const float* __restrict__ Wq,
    const float* __restrict__ Wk, const float* __restrict__ Wv,
    const float* __restrict__ W1, const float* __restrict__ W2,
    const float* __restrict__ bq, const float* __restrict__ bk,
    const float* __restrict__ bv, bf16* __restrict__ seq_bf,
    bf16* __restrict__ qkvT, bf16* __restrict__ W1T, bf16* __restrict__ W2T,
    float* __restrict__ bqkv) {
  __shared__ float tile[32][33];
  const int blk = blockIdx.x;
  const int tid = threadIdx.x;

  if (blk < 2048) {  // cvt f32->bf16
    int i = blk * 256 + tid;
    float4 a = ((const float4*)seq)[2 * i];
    float4 b = ((const float4*)seq)[2 * i + 1];
    bf16x8 v;
    v[0] = (bf16)a.x; v[1] = (bf16)a.y; v[2] = (bf16)a.z; v[3] = (bf16)a.w;
    v[4] = (bf16)b.x; v[5] = (bf16)b.y; v[6] = (bf16)b.z; v[7] = (bf16)b.w;
    ((bf16x8*)seq_bf)[i] = v;
    return;
  }

  const int tx = tid & 31, ty = tid >> 5;  // (32,8) remap for transposes
  const float* in;
  bf16* out;
  int N, K, bx, by;
  if (blk < 3840) {
    if (blk < 2816) {  // Wq/Wk/Wv: 256 blocks each, N=K=512
      int t = blk - 2048;
      int which = t >> 8;
      int r = t & 255;
      in = which == 0 ? Wq : (which == 1 ? Wk : Wv);
      out = qkvT + (long)which * 512 * 512;
      N = 512; K = 512;
      bx = r & 15; by = r >> 4;
    } else {  // W1: N=2048, K=512, grid (64,16)
      int t = blk - 2816;
      in = W1; out = W1T; N = 2048; K = 512;
      bx = t & 63; by = t >> 6;
    }
  } else if (blk < 4864) {  // W2: N=512, K=2048, grid (16,64)
    int t = blk - 3840;
    in = W2; out = W2T; N = 512; K = 2048;
    bx = t & 15; by = t >> 4;
  } else {  // concat bias
    int i = (blk - 4864) * 256 + tid;
    if (i < 512) bqkv[i] = bq[i];
    else if (i < 1024) bqkv[i] = bk[i - 512];
    else if (i < 1536) bqkv[i] = bv[i - 1024];
    return;
  }

  int n0 = bx * 32, k0 = by * 32;
#pragma unroll
  for (int i = 0; i < 4; i++) tile[ty + i * 8][tx] = in[(long)(k0 + ty + i * 8) * N + n0 + tx];
  __syncthreads();
#pragma unroll
  for (int i = 0; i < 4; i++)
    out[(long)(n0 + ty + i * 8) * K + k0 + tx] = (bf16)tile[tx][ty + i * 8];
}

// ---------------------------------------------------------------------------
// C[M,N](OutT) = act(A[M,K](bf16) @ BT[N,K](bf16)^T + bias) [+ resid]
// BM=128 x BN (128|64) tile, BK (64|128), 4 waves (2x2), 16x16x32 MFMA.
// global_load_lds staging: linear LDS dest, XOR-swizzled (involution)
// source, swizzled reads (rule #21). R5-proven sync structure -- BN/BK are
// parameter changes (two-lane discipline). BK=128 halves barrier-drain
// events for long-K shapes (FFN2: 32->16 tiles); LDS 48KB keeps 2 blocks/CU
// (grid-limited), dodging m132's occupancy trap.
// 1-D grid + bijective XCD-chunk swizzle (T1; requires nwg%8==0).
// VSPLIT (BN=128 only): blocks with bcol>=1024 write the V third transposed
// into vt[b*8+h][d][s] instead of C.
template <int ACT, int RESID, int VSPLIT, int BN, int BK, typename OutT>
__global__ __launch_bounds__(256, 2)
void gemm_bt(const bf16* __restrict__ A, const bf16* __restrict__ BT,
             const float* __restrict__ bias, const bf16* __restrict__ resid,
             OutT* __restrict__ C, bf16* __restrict__ vt,
             int K, int lda, int ldb, int ldc, int gx) {
  constexpr int NT = BN / 32;   // per-wave n-tiles of 16 (wc splits BN in 2)
  constexpr int KF = BK / 32;   // 16x16x32 k-fragments per K-tile
  constexpr int CPR = BK / 8;   // 16B chunks per LDS row
  constexpr int BK2 = BK * 2;   // bytes per LDS row
  __shared__ __align__(16) char As[128 * BK2];
  __shared__ __align__(16) char Bs[BN * BK2];
  const int tid = threadIdx.x;
  const int l = tid & 63, w = tid >> 6;
  const int lrow = l & 15, lhi = l >> 4;
  const int wr = w >> 1, wc = w & 1;
  // XCD swizzle: XCD(bid)=bid%8; give each XCD a contiguous work-id chunk
  const int bid = blockIdx.x;
  const int nwg = gridDim.x;  // multiple of 8
  const int wg = (bid & 7) * (nwg >> 3) + (bid >> 3);
  const long brow = (long)(wg / gx) * 128;
  const long bcol = (long)(wg % gx) * BN;

  f32x4 zero = {0.f, 0.f, 0.f, 0.f};
  f32x4 acc[4][NT];
#pragma unroll
  for (int m = 0; m < 4; m++)
#pragma unroll
    for (int n = 0; n < NT; n++) acc[m][n] = zero;

  for (int kt = 0; kt < K; kt += BK) {
    __syncthreads();
#pragma unroll
    for (int c = 0; c < CPR / 2; c++) {  // A: 128*CPR chunks (16B each)
      int idx = c * 256 + tid;
      int row = idx / CPR;
      int cole = ((idx & (CPR - 1)) ^ (row & (CPR - 1))) * 8;
      ASYNC16(A + (brow + row) * lda + kt + cole, As + idx * 16);
    }
#pragma unroll
    for (int c = 0; c < (BN * CPR) / 256; c++) {  // B: BN*CPR chunks
      int idx = c * 256 + tid;
      int row = idx / CPR;
      int cole = ((idx & (CPR - 1)) ^ (row & (CPR - 1))) * 8;
      ASYNC16(BT + (bcol + row) * ldb + kt + cole, Bs + idx * 16);
    }
    __syncthreads();  // compiler drains vmcnt before s_barrier
    bf16x8 af[4][KF], bfr[NT][KF];
#pragma unroll
    for (int m = 0; m < 4; m++) {
      int row = wr * 64 + m * 16 + lrow;
      int base = row * BK2 + lhi * 16;
      int sw = (row & (CPR - 1)) << 4;
#pragma unroll
      for (int kf = 0; kf < KF; kf++)
        af[m][kf] = *(const bf16x8*)(As + ((base + kf * 64) ^ sw));
    }
#pragma unroll
    for (int n = 0; n < NT; n++) {
      int row = wc * (16 * NT) + n * 16 + lrow;
      int base = row * BK2 + lhi * 16;
      int sw = (row & (CPR - 1)) << 4;
#pragma unroll
      for (int kf = 0; kf < KF; kf++)
        bfr[n][kf] = *(const bf16x8*)(Bs + ((base + kf * 64) ^ sw));
    }
#pragma unroll
    for (int m = 0; m < 4; m++)
#pragma unroll
      for (int n = 0; n < NT; n++)
#pragma unroll
        for (int kf = 0; kf < KF; kf++)
          acc[m][n] = MFMA16(af[m][kf], bfr[n][kf], acc[m][n]);
  }

  if (VSPLIT && bcol >= 1024) {
    // V third -> vt[b*8+h][d][s]; rows brow.. are b*1024+s, cols are 1024+h*64+d
#pragma unroll
    for (int m = 0; m < 4; m++) {
#pragma unroll
      for (int n = 0; n < NT; n++) {
        long col = bcol + wc * (16 * NT) + n * 16 + lrow;
        float bv = bias[col];
        int cc = (int)col - 1024;
        int hh = cc >> 6, dd = cc & 63;
        long row0 = brow + wr * 64 + m * 16 + lhi * 4;
        int b = (int)(row0 >> 10), s0 = (int)(row0 & 1023);
        bf16x4 v4;
#pragma unroll
        for (int r = 0; r < 4; r++) v4[r] = (bf16)(acc[m][n][r] + bv);
        *(bf16x4*)(vt + ((long)(b * 8 + hh) * 64 + dd) * 1024 + s0) = v4;
      }
    }
    return;
  }

#pragma unroll
  for (int m = 0; m < 4; m++) {
#pragma unroll
    for (int n = 0; n < NT; n++) {
      long col = bcol + wc * (16 * NT) + n * 16 + lrow;
      float bv = bias[col];
#pragma unroll
      for (int r = 0; r < 4; r++) {
        long row = brow + wr * 64 + m * 16 + lhi * 4 + r;
        float v = acc[m][n][r] + bv;
        if (ACT) v = v > 0.f ? v : 0.01f * v;
        if (RESID) v += (float)resid[row * ldc + col];
        C[row * ldc + col] = (OutT)v;
      }
    }
  }
}

// ---------------------------------------------------------------------------
// Flash attention, swapped-operand 32x32x16 structure (T12) -- R8-proven
// math, XCD-affine grid: dims are (h, b, qx) so linear id = h + 8b + 64qx
// and XCD = id%8 = h. All q-blocks/batches of head h share one XCD; per-XCD
// K/V working set = 2MB <= 4MB L2 (R13 confirmed: FETCH 73.8 -> 12.3MB).
// Counted-vmcnt K/V dbuf; softmax in-register; P repack via pk-casts +
// distinct-value PLSWAPs. Quirk: softmax FIRST, then /sqrt(512).
// 4 waves, wave owns 32 q-rows; KVBLK=64.
__global__ __launch_bounds__(256, 2)
void attn_fwd(const bf16* __restrict__ QKV, const bf16* __restrict__ Vtg,
              bf16* __restrict__ attn_out) {
  __shared__ __align__(16) char Ks[2][64 * 128];  // [key][d] swizzled, dbuf
  __shared__ __align__(16) char Vs[2][64 * 128];  // [d][s] swizzled, dbuf
  const int tid = threadIdx.x;
  const int l = tid & 63, w = tid >> 6;
  const int q = l & 31, hi = l >> 5;
  const int h = blockIdx.x;                        // XCD = h
  const long rowbase = (long)blockIdx.y * 1024;    // batch b
  const int q0 = blockIdx.z * 128;                 // q-tile
  const float LOG2E = 1.4426950408889634f;

  const bf16* Kb = QKV + 512;
  const bf16* Vb = Vtg + ((long)blockIdx.y * 8 + h) * 64 * 1024;  // [64][1024]

  auto stage = [&](int buf, int kt) {
#pragma unroll
    for (int c = 0; c < 2; c++) {
      int idx = c * 256 + tid;
      int row = idx >> 3;
      int cole = ((idx & 7) ^ (row & 7)) * 8;
      ASYNC16(Kb + (rowbase + kt * 64 + row) * 1536 + h * 64 + cole, Ks[buf] + idx * 16);
      ASYNC16(Vb + row * 1024 + kt * 64 + cole, Vs[buf] + idx * 16);
    }
  };

  // Q fragments (B-operand): aq[sd][j] = Q[qrow][sd*16 + hi*8 + j]
  bf16x8 aq[4];
  {
    long qrow = rowbase + q0 + w * 32 + q;
    const bf16* p = QKV + qrow * 1536 + h * 64 + hi * 8;
    aq[0] = *(const bf16x8*)(p);
    aq[1] = *(const bf16x8*)(p + 16);
    aq[2] = *(const bf16x8*)(p + 32);
    aq[3] = *(const bf16x8*)(p + 48);
  }
  // pin Q loads complete BEFORE the pipeline starts, so the compiler's
  // load-use waitcnt can't drain the prefetch queue inside the loop
  asm volatile("" ::"v"(aq[0]), "v"(aq[1]), "v"(aq[2]), "v"(aq[3]));

  f32x16 o0, o1;
#pragma unroll
  for (int i = 0; i < 16; i++) { o0[i] = 0.f; o1[i] = 0.f; }
  float m_run = -1e30f, l_run = 0.f;

  stage(0, 0);
  int cur = 0;

  for (int kt = 0; kt < 16; ++kt) {
    // barrier A: all waves done READING buf cur^1 -> safe to overwrite
    asm volatile("" ::: "memory");
    __builtin_amdgcn_s_barrier();
    asm volatile("" ::: "memory");
    stage(cur ^ 1, (kt + 1) & 15);
    asm volatile("s_waitcnt vmcnt(4)" ::: "memory");  // older 4 (tile kt) landed
    __builtin_amdgcn_sched_barrier(0);
    __builtin_amdgcn_s_barrier();  // barrier B
    asm volatile("" ::: "memory");

    const char* Kc = Ks[cur];
    const char* Vc = Vs[cur];

    // S^T = K Q^T : lane holds col q=l&31, 32 keys across regs/halves
    f32x16 s0, s1;
#pragma unroll
    for (int i = 0; i < 16; i++) { s0[i] = 0.f; s1[i] = 0.f; }
    __builtin_amdgcn_s_setprio(1);
#pragma unroll
    for (int t = 0; t < 2; t++) {
      f32x16 c;
#pragma unroll
      for (int i = 0; i < 16; i++) c[i] = 0.f;
      int row = t * 32 + q;
      int sw = (row & 7) << 4;
#pragma unroll
      for (int sd = 0; sd < 4; sd++) {
        bf16x8 kf = *(const bf16x8*)(Kc + ((row * 128 + sd * 32 + hi * 16) ^ sw));
        c = MFMA32(kf, aq[sd], c);
      }
      if (t) s1 = c; else s0 = c;
    }
    __builtin_amdgcn_s_setprio(0);

    // in-register online softmax (lane owns q-row; halves share via 1 shfl)
    float tmax = s0[0];
#pragma unroll
    for (int i = 1; i < 16; i++) tmax = fmaxf(tmax, s0[i]);
#pragma unroll
    for (int i = 0; i < 16; i++) tmax = fmaxf(tmax, s1[i]);
    tmax = fmaxf(tmax, __shfl_xor(tmax, 32));
    float mn = fmaxf(m_run, tmax);
    float al = __builtin_exp2f((m_run - mn) * LOG2E);
    float mh = mn * LOG2E;
    m_run = mn;
    float p0[16], p1[16];
    float ps = 0.f;
#pragma unroll
    for (int i = 0; i < 16; i++) {
      p0[i] = __builtin_exp2f(__builtin_fmaf(s0[i], LOG2E, -mh));
      ps += p0[i];
    }
#pragma unroll
    for (int i = 0; i < 16; i++) {
      p1[i] = __builtin_exp2f(__builtin_fmaf(s1[i], LOG2E, -mh));
      ps += p1[i];
    }
    ps += __shfl_xor(ps, 32);
    l_run = l_run * al + ps;
#pragma unroll
    for (int i = 0; i < 16; i++) { o0[i] *= al; o1[i] *= al; }

    // repack P (C-layout) -> 4 B-fragments pa[ks] (k = ks*16 + hi*8 + j)
    bf16x8 pa[4];
    {
      unsigned a0 = pk2(p0[0], p0[1]), b0 = pk2(p0[4], p0[5]);
      unsigned a1 = pk2(p0[2], p0[3]), b1 = pk2(p0[6], p0[7]);
      unsigned a2 = pk2(p0[8], p0[9]), b2 = pk2(p0[12], p0[13]);
      unsigned a3 = pk2(p0[10], p0[11]), b3 = pk2(p0[14], p0[15]);
      PLSWAP(a0, b0); PLSWAP(a1, b1); PLSWAP(a2, b2); PLSWAP(a3, b3);
      uint4 w0 = {a0, a1, b0, b1};
      uint4 w1 = {a2, a3, b2, b3};
      pa[0] = __builtin_bit_cast(bf16x8, w0);
      pa[1] = __builtin_bit_cast(bf16x8, w1);
      unsigned c0 = pk2(p1[0], p1[1]), d0 = pk2(p1[4], p1[5]);
      unsigned c1 = pk2(p1[2], p1[3]), d1 = pk2(p1[6], p1[7]);
      unsigned c2 = pk2(p1[8], p1[9]), d2 = pk2(p1[12], p1[13]);
      unsigned c3 = pk2(p1[10], p1[11]), d3 = pk2(p1[14], p1[15]);
      PLSWAP(c0, d0); PLSWAP(c1, d1); PLSWAP(c2, d2); PLSWAP(c3, d3);
      uint4 w2 = {c0, c1, d0, d1};
      uint4 w3 = {c2, c3, d2, d3};
      pa[2] = __builtin_bit_cast(bf16x8, w2);
      pa[3] = __builtin_bit_cast(bf16x8, w3);
    }

    // O^T += V^T P^T : lane holds col q, d-rows in regs
    __builtin_amdgcn_s_setprio(1);
    {
      int row = q;  // sub 0: d rows 0..31
      int sw = (row & 7) << 4;
#pragma unroll
      for (int ks = 0; ks < 4; ks++) {
        bf16x8 vf = *(const bf16x8*)(Vc + ((row * 128 + ks * 32 + hi * 16) ^ sw));
        o0 = MFMA32(vf, pa[ks], o0);
      }
      row = 32 + q;  // sub 1: d rows 32..63
      sw = (row & 7) << 4;
#pragma unroll
      for (int ks = 0; ks < 4; ks++) {
        bf16x8 vf = *(const bf16x8*)(Vc + ((row * 128 + ks * 32 + hi * 16) ^ sw));
        o1 = MFMA32(vf, pa[ks], o1);
      }
    }
    __builtin_amdgcn_s_setprio(0);
    cur ^= 1;
  }

  // epilogue: quirk scale 1/sqrt(512) AFTER softmax; O^T -> row-major out
  float fac = 0.044194173824159216f / l_run;
  long qrow = rowbase + q0 + w * 32 + q;
  bf16* op = attn_out + qrow * 512 + h * 64;
#pragma unroll
  for (int t = 0; t < 4; t++) {
    bf16x4 v0, v1;
#pragma unroll
    for (int u = 0; u < 4; u++) {
      v0[u] = (bf16)(o0[4 * t + u] * fac);
      v1[u] = (bf16)(o1[4 * t + u] * fac);
    }
    *(bf16x4*)(op + 8 * t + 4 * hi) = v0;
    *(bf16x4*)(op + 32 + 8 * t + 4 * hi) = v1;
  }
}

// ---------------------------------------------------------------------------
// ln = LayerNorm(seq_f32 + attn_bf16) * gamma + beta   (one block per row)
__global__ __launch_bounds__(256) void ln_kernel(const float* __restrict__ seq,
                                                 const bf16* __restrict__ attn,
                                                 const float* __restrict__ gamma,
                                                 const float* __restrict__ beta,
                                                 bf16* __restrict__ out) {
  int row = blockIdx.x;
  int tid = threadIdx.x;
  long base = (long)row * 512;
  float x0 = seq[base + tid] + (float)attn[base + tid];
  float x1 = seq[base + 256 + tid] + (float)attn[base + 256 + tid];
  float s = x0 + x1, ss = x0 * x0 + x1 * x1;
#pragma unroll
  for (int mm = 1; mm < 64; mm <<= 1) {
    s += __shfl_xor(s, mm);
    ss += __shfl_xor(ss, mm);
  }
  __shared__ float red[8];
  int w = tid >> 6, l = tid & 63;
  if (l == 0) { red[w] = s; red[4 + w] = ss; }
  __syncthreads();
  s = red[0] + red[1] + red[2] + red[3];
  ss = red[4] + red[5] + red[6] + red[7];
  float mu = s * (1.f / 512.f);
  float var = ss * (1.f / 512.f) - mu * mu;
  float rs = rsqrtf(var + 1e-5f);
  out[base + tid] = (bf16)((x0 - mu) * rs * gamma[tid] + beta[tid]);
  out[base + 256 + tid] = (bf16)((x1 - mu) * rs * gamma[tid + 256] + beta[tid + 256]);
}

// ---------------------------------------------------------------------------
extern "C" void kernel_launch(void* const* d_in, const int* in_sizes, int n_in,
                              void* d_out, int out_size, void* d_ws, size_t ws_size,
                              hipStream_t stream) {
  const float* seq = (const float*)d_in[0];
  const float* Wq = (const float*)d_in[1];
  const float* bq = (const float*)d_in[2];
  const float* Wk = (const float*)d_in[3];
  const float* bk = (const float*)d_in[4];
  const float* Wv = (const float*)d_in[5];
  const float* bv = (const float*)d_in[6];
  const float* W1 = (const float*)d_in[7];
  const float* b1 = (const float*)d_in[8];
  const float* W2 = (const float*)d_in[9];
  const float* b2 = (const float*)d_in[10];
  const float* gamma = (const float*)d_in[11];
  const float* beta = (const float*)d_in[12];
  float* out = (float*)d_out;  // reference output dtype is float32

  // workspace layout (bytes)
  char* ws = (char*)d_ws;
  if (ws_size < 89659392u) return;  // loud failure signature if ws too small
  bf16* seq_bf = (bf16*)(ws + 0);          //  8192x512   bf16  (8,388,608)
  bf16* qkvT = (bf16*)(ws + 8388608);      //  1536x512   bf16  (1,572,864)
  bf16* W1T = (bf16*)(ws + 9961472);       //  2048x512   bf16  (2,097,152)
  bf16* W2T = (bf16*)(ws + 12058624);      //  512x2048   bf16  (2,097,152)
  float* bqkv = (float*)(ws + 14155776);   //  1536       f32   (6,144)
  bf16* QKV = (bf16*)(ws + 14161920);      //  8192x1536  bf16  (25,165,824; V third unused)
  bf16* attn = (bf16*)(ws + 39327744);     //  8192x512   bf16  (8,388,608)
  bf16* ln = (bf16*)(ws + 47716352);       //  8192x512   bf16  (8,388,608)
  bf16* hidden = (bf16*)(ws + 56104960);   //  8192x2048  bf16  (33,554,432)
  bf16* vt = (bf16*)(ws + 56104960);       //  64x64x1024 bf16  (8.4MB, aliases hidden:
                                           //  written by QKV gemm, read by attn,
                                           //  dead before FFN1 overwrites hidden)

  // single fused pre-pass launch (replaces 5 serialized small launches)
  prep_kernel<<<4870, 256, 0, stream>>>(seq, Wq, Wk, Wv, W1, W2, bq, bk, bv,
                                        seq_bf, qkvT, W1T, W2T, bqkv);

  // QKV = seq_bf @ [Wq|Wk|Wv] + bias : M=8192 N=1536 K=512 (768 blocks, %8==0)
  // Q,K cols -> QKV row-major; V cols -> vt[b*8+h][d][s] (transposed, fused)
  gemm_bt<0, 0, 1, 128, 64, bf16><<<768, 256, 0, stream>>>(
      seq_bf, qkvT, bqkv, (const bf16*)nullptr, QKV, vt, 512, 512, 512, 1536, 12);
  // grid (h, b, qx): XCD = linear%8 = h -> per-XCD K/V set 2MB, L2-resident
  attn_fwd<<<dim3(8, 8, 8), 256, 0, stream>>>(QKV, vt, attn);
  ln_kernel<<<8192, 256, 0, stream>>>(seq, attn, gamma, beta, ln);
  // hidden = leaky_relu(ln @ W1 + b1) : M=8192 N=2048 K=512 (1024 blocks)
  gemm_bt<1, 0, 0, 128, 64, bf16><<<1024, 256, 0, stream>>>(
      ln, W1T, b1, (const bf16*)nullptr, hidden, (bf16*)nullptr, 512, 512, 512, 2048, 16);
  // out = ln + hidden @ W2 + b2 : M=8192 N=512 K=2048
  // BN=64 (2 blocks/CU) + BK=128 (16 K-tiles: half the barrier drains)
  gemm_bt<0, 1, 0, 64, 128, float><<<512, 256, 0, stream>>>(
      hidden, W2T, b2, ln, out, (bf16*)nullptr, 2048, 2048, 2048, 512, 8);
}